// Round 5
// baseline (321.068 us; speedup 1.0000x reference)
//
#include <hip/hip_runtime.h>
#include <hip/hip_bf16.h>
#include <math.h>

#define BATCH 16
#define LSEQ 4096
#define DMODEL 256
#define NST 16
#define LC 32
#define NCHUNK (LSEQ / LC)    // 128
#define MROWS (BATCH * LSEQ)  // 65536
#define LOG2E 1.44269504088896340736f

typedef float f32x4 __attribute__((ext_vector_type(4)));
typedef short bf16x8 __attribute__((ext_vector_type(8)));

__device__ __forceinline__ float silu_f(float v) { return v / (1.f + __expf(-v)); }
__device__ __forceinline__ float softplus_f(float v) {
  return fmaxf(v, 0.f) + log1pf(__expf(-fabsf(v)));
}

// fp32 -> bf16 rne; bf16 -> fp32; fp32 <-> fp16 bits
__device__ __forceinline__ uint bf16rne(float f) {
  uint u = __float_as_uint(f);
  return (u + 0x7fffu + ((u >> 16) & 1u)) >> 16;
}
__device__ __forceinline__ float bf2f(ushort u) {
  return __uint_as_float((uint)u << 16);
}
__device__ __forceinline__ ushort f2h(float v) {
  _Float16 h = (_Float16)v;
  return __builtin_bit_cast(ushort, h);
}
__device__ __forceinline__ float h2f(ushort u) {
  return (float)__builtin_bit_cast(_Float16, u);
}
__device__ __forceinline__ uint pk2(float x, float y) {
  return bf16rne(x) | (bf16rne(y) << 16);
}
__device__ __forceinline__ uint4 pk8(float4 a, float4 b) {
  uint4 r;
  r.x = pk2(a.x, a.y);
  r.y = pk2(a.z, a.w);
  r.z = pk2(b.x, b.y);
  r.w = pk2(b.z, b.w);
  return r;
}

// async global(bf16)->LDS, 16 B per lane (dest = wave-uniform base + lane*16)
__device__ __forceinline__ void glds16(const ushort* g, char* l) {
  __builtin_amdgcn_global_load_lds(
      (const __attribute__((address_space(1))) void*)g,
      (__attribute__((address_space(3))) void*)l, 16, 0, 0);
}

// ---------------------------------------------------------------------------
// Weight fp32->bf16 convert. dst layout (ushort offsets):
//   [0,131072) W_in | [131072,196608) W_delta | [196608,262144) W_out
//   [262144,266240) W_B | [266240,270336) W_C
// ---------------------------------------------------------------------------
__global__ __launch_bounds__(256) void cvt_weights(
    const float* __restrict__ Win, const float* __restrict__ Wd,
    const float* __restrict__ Wo, const float* __restrict__ WB,
    const float* __restrict__ WC, ushort* __restrict__ dst) {
  size_t i = ((size_t)blockIdx.x * 256 + threadIdx.x) * 8;
  if (i >= 270336) return;
  const float* s;
  size_t o;
  if (i < 131072)      { s = Win; o = i; }
  else if (i < 196608) { s = Wd;  o = i - 131072; }
  else if (i < 262144) { s = Wo;  o = i - 196608; }
  else if (i < 266240) { s = WB;  o = i - 262144; }
  else                 { s = WC;  o = i - 266240; }
  float4 a = *(const float4*)(s + o);
  float4 b = *(const float4*)(s + o + 4);
  *(uint4*)(dst + i) = pk8(a, b);
}

// ---------------------------------------------------------------------------
// MFMA GEMM: out[M,N] = A[M,256] @ B[N,256]^T (+bias, per-MODE epilogue)
// Tile 64 x 256, 256 thr (4 waves), BK=32, 8 K-steps, dbuf LDS, 1 barrier/step.
// B always bf16 via global_load_lds (pre-swizzled source).
// MODE 0: A fp32 (x), reg-staged. N=512 via gridDim.x. col<256 -> x_in fp32;
//         col>=256 -> silu(z) bf16.
// MODE 1: A bf16 (xc) via glds. out = softplus(v+bias) as fp16 (delta).
// MODE 3: A bf16 (y_pre) via glds. out = v+bias fp32 (final).
// ---------------------------------------------------------------------------
template <int MODE>
__global__ __launch_bounds__(256, 4) void gemm2(
    const void* __restrict__ Av, const ushort* __restrict__ Bbf,
    const float* __restrict__ bias, void* __restrict__ out0v,
    void* __restrict__ out1v) {
  constexpr int KD = 256;
  __shared__ char smem[40960];  // buf stride 20480: A 4KB @0, B 16KB @4096
  const int tid = threadIdx.x;
  const int lane = tid & 63, wid = tid >> 6;
  const int M0 = blockIdx.y * 64;
  const int N0 = blockIdx.x * 256;

  const int rA = tid >> 2, cA = tid & 3;
  const int sA = (rA + (rA >> 2)) & 3;
  const int ldsAoff = rA * 64 + ((cA ^ sA) * 16);

  const float* gA32 = nullptr;
  const ushort* gA16 = nullptr;
  if constexpr (MODE == 0)
    gA32 = (const float*)Av + (size_t)(M0 + rA) * KD + cA * 8;
  else
    gA16 = (const ushort*)Av + (size_t)(M0 + rA) * KD + ((cA ^ sA) * 8);
  const ushort* gB = Bbf + (size_t)(N0 + rA) * KD + ((cA ^ sA) * 8);

  f32x4 acc[4][4];
#pragma unroll
  for (int i = 0; i < 4; ++i)
#pragma unroll
    for (int j = 0; j < 4; ++j) acc[i][j] = {0.f, 0.f, 0.f, 0.f};

  // prologue: stage step 0 into buf0
  {
#pragma unroll
    for (int i = 0; i < 4; ++i)
      glds16(gB + (size_t)i * 64 * KD, smem + 4096 + i * 4096 + wid * 1024);
    if constexpr (MODE == 0) {
      float4 a0 = *(const float4*)(gA32);
      float4 a1 = *(const float4*)(gA32 + 4);
      *(uint4*)(smem + ldsAoff) = pk8(a0, a1);
    } else {
      glds16(gA16, smem + wid * 1024);
    }
  }
  __syncthreads();

  for (int step = 0; step < 8; ++step) {
    const int cur = step & 1;
    char* bufc = smem + cur * 20480;
    char* bufn = smem + (cur ^ 1) * 20480;
    float4 na0, na1;
    if (step < 7) {
      const int k0 = (step + 1) * 32;
#pragma unroll
      for (int i = 0; i < 4; ++i)
        glds16(gB + (size_t)i * 64 * KD + k0,
               bufn + 4096 + i * 4096 + wid * 1024);
      if constexpr (MODE == 0) {
        na0 = *(const float4*)(gA32 + k0);
        na1 = *(const float4*)(gA32 + k0 + 4);
      } else {
        glds16(gA16 + k0, bufn + wid * 1024);
      }
    }
    bf16x8 af[4], bfr[4];
#pragma unroll
    for (int i = 0; i < 4; ++i) {
      int r = i * 16 + (lane & 15);
      int slot = (lane >> 4) ^ ((r + (r >> 2)) & 3);
      af[i] = *(const bf16x8*)(bufc + r * 64 + slot * 16);
    }
#pragma unroll
    for (int j = 0; j < 4; ++j) {
      int r = wid * 64 + j * 16 + (lane & 15);
      int slot = (lane >> 4) ^ ((r + (r >> 2)) & 3);
      bfr[j] = *(const bf16x8*)(bufc + 4096 + r * 64 + slot * 16);
    }
#pragma unroll
    for (int i = 0; i < 4; ++i)
#pragma unroll
      for (int j = 0; j < 4; ++j)
        acc[i][j] = __builtin_amdgcn_mfma_f32_16x16x32_bf16(af[i], bfr[j],
                                                            acc[i][j], 0, 0, 0);
    if constexpr (MODE == 0) {
      if (step < 7) *(uint4*)(bufn + ldsAoff) = pk8(na0, na1);
    }
    __syncthreads();
  }

  // epilogue
  const int rbase = (lane >> 4) * 4;
  const int cn = lane & 15;
#pragma unroll
  for (int i = 0; i < 4; ++i) {
#pragma unroll
    for (int j = 0; j < 4; ++j) {
      int col = N0 + wid * 64 + j * 16 + cn;
      float bs = bias[col];
#pragma unroll
      for (int r = 0; r < 4; ++r) {
        int row = M0 + i * 16 + rbase + r;
        float v = acc[i][j][r] + bs;
        if constexpr (MODE == 0) {
          if (col < DMODEL)
            ((float*)out0v)[(size_t)row * DMODEL + col] = v;
          else
            ((ushort*)out1v)[(size_t)row * DMODEL + (col - DMODEL)] =
                (ushort)bf16rne(silu_f(v));
        } else if constexpr (MODE == 1) {
          ((ushort*)out0v)[(size_t)row * DMODEL + col] = f2h(softplus_f(v));
        } else {
          ((float*)out0v)[(size_t)row * DMODEL + col] = v;
        }
      }
    }
  }
}

// ---------------------------------------------------------------------------
// bc GEMM: out[M,32](bf16) = xc(bf16) @ wbc[32,256]^T. Tile 128 x 32, 256 thr.
// B (16 KB) staged once via glds; A bf16 via glds, dbuf.
// ---------------------------------------------------------------------------
__global__ __launch_bounds__(256, 4) void gemm_bc2(
    const ushort* __restrict__ Abf, const ushort* __restrict__ wbc,
    ushort* __restrict__ out0) {
  constexpr int KD = 256;
  __shared__ char smem[32768];  // B 16KB @0; A dbuf @16384 (8KB each)
  const int tid = threadIdx.x, lane = tid & 63, wid = tid >> 6;
  const int M0 = blockIdx.x * 128;

  {  // stage whole B once
    const int rB = tid >> 5, cB = tid & 31;
    const ushort* gB = wbc + (size_t)rB * KD + ((cB ^ (rB & 7)) * 8);
#pragma unroll
    for (int i = 0; i < 4; ++i)
      glds16(gB + (size_t)(8 * i) * KD, smem + (8 * i + 2 * wid) * 512);
  }

  const int rA = tid >> 2, cA = tid & 3;
  const int sA = (rA + (rA >> 2)) & 3;
  const ushort* gA = Abf + (size_t)(M0 + rA) * KD + ((cA ^ sA) * 8);

  f32x4 acc[2][2];
#pragma unroll
  for (int q = 0; q < 2; ++q)
#pragma unroll
    for (int j = 0; j < 2; ++j) acc[q][j] = {0.f, 0.f, 0.f, 0.f};

  {  // prologue A step 0 -> buf0 (rows 0..63 then 64..127; same swizzle)
    glds16(gA, smem + 16384 + wid * 1024);
    glds16(gA + (size_t)64 * KD, smem + 16384 + 4096 + wid * 1024);
  }
  __syncthreads();

  for (int step = 0; step < 8; ++step) {
    const int cur = step & 1;
    char* bufc = smem + 16384 + cur * 8192;
    char* bufn = smem + 16384 + (cur ^ 1) * 8192;
    if (step < 7) {
      const int k0 = (step + 1) * 32;
      glds16(gA + k0, bufn + wid * 1024);
      glds16(gA + (size_t)64 * KD + k0, bufn + 4096 + wid * 1024);
    }
    bf16x8 af[2], bfr[2];
#pragma unroll
    for (int q = 0; q < 2; ++q) {
      int r = wid * 32 + q * 16 + (lane & 15);
      int slot = (lane >> 4) ^ ((r + (r >> 2)) & 3);
      af[q] = *(const bf16x8*)(bufc + r * 64 + slot * 16);
    }
#pragma unroll
    for (int j = 0; j < 2; ++j) {
      int r = j * 16 + (lane & 15);
      int ch = step * 4 + (lane >> 4);
      int slot = ch ^ (r & 7);
      bfr[j] = *(const bf16x8*)(smem + r * 512 + slot * 16);
    }
#pragma unroll
    for (int q = 0; q < 2; ++q)
#pragma unroll
      for (int j = 0; j < 2; ++j)
        acc[q][j] = __builtin_amdgcn_mfma_f32_16x16x32_bf16(af[q], bfr[j],
                                                            acc[q][j], 0, 0, 0);
    __syncthreads();
  }

  const int rbase = (lane >> 4) * 4, cn = lane & 15;
#pragma unroll
  for (int q = 0; q < 2; ++q)
#pragma unroll
    for (int j = 0; j < 2; ++j)
#pragma unroll
      for (int r = 0; r < 4; ++r) {
        int row = M0 + wid * 32 + q * 16 + rbase + r;
        out0[(size_t)row * 32 + j * 16 + cn] = (ushort)bf16rne(acc[q][j][r]);
      }
}

// ---------------------------------------------------------------------------
// Depthwise conv (k=3, pad=1) + bias + silu. fp32 in, bf16 out.
// 256 thr: 8 l x 32 d-groups of 8. grid = MROWS/8.
// ---------------------------------------------------------------------------
__global__ __launch_bounds__(256) void conv_silu_k(
    const float* __restrict__ xin, const float* __restrict__ conv_w,
    const float* __restrict__ conv_b, ushort* __restrict__ xc) {
  __shared__ float w0[DMODEL], w1[DMODEL], w2[DMODEL], cb[DMODEL];
  const int tid = threadIdx.x;
  w0[tid] = conv_w[tid * 3 + 0];
  w1[tid] = conv_w[tid * 3 + 1];
  w2[tid] = conv_w[tid * 3 + 2];
  cb[tid] = conv_b[tid];
  __syncthreads();

  const int row = blockIdx.x * 8 + (tid >> 5);
  const int l = row & (LSEQ - 1);
  const int d0 = (tid & 31) * 8;
  const size_t base = (size_t)row * DMODEL + d0;

  float4 zf = {0.f, 0.f, 0.f, 0.f};
  float4 m0 = zf, m1 = zf, p0 = zf, p1 = zf;
  if (l > 0) {
    m0 = *(const float4*)(xin + base - DMODEL);
    m1 = *(const float4*)(xin + base - DMODEL + 4);
  }
  float4 c0 = *(const float4*)(xin + base);
  float4 c1 = *(const float4*)(xin + base + 4);
  if (l < LSEQ - 1) {
    p0 = *(const float4*)(xin + base + DMODEL);
    p1 = *(const float4*)(xin + base + DMODEL + 4);
  }
  float mv[8] = {m0.x, m0.y, m0.z, m0.w, m1.x, m1.y, m1.z, m1.w};
  float cv[8] = {c0.x, c0.y, c0.z, c0.w, c1.x, c1.y, c1.z, c1.w};
  float pv[8] = {p0.x, p0.y, p0.z, p0.w, p1.x, p1.y, p1.z, p1.w};
  float ov[8];
#pragma unroll
  for (int k = 0; k < 8; ++k) {
    int d = d0 + k;
    float o = fmaf(w0[d], mv[k], fmaf(w1[d], cv[k], fmaf(w2[d], pv[k], cb[d])));
    ov[k] = silu_f(o);
  }
  uint4 r;
  r.x = pk2(ov[0], ov[1]);
  r.y = pk2(ov[2], ov[3]);
  r.z = pk2(ov[4], ov[5]);
  r.w = pk2(ov[6], ov[7]);
  *(uint4*)(xc + base) = r;
}

// ---------------------------------------------------------------------------
// Scan pass 1: per (b, chunk) block, 256 thr (one per d), LC=32.
// delta fp16, xc bf16, bc bf16 in; hout/cumA fp32 out.
// ---------------------------------------------------------------------------
__global__ __launch_bounds__(256, 8) void scan_pass1(
    const ushort* __restrict__ delta, const ushort* __restrict__ xc,
    const ushort* __restrict__ bc, const float* __restrict__ A_log,
    float* __restrict__ hout, float* __restrict__ cumA) {
  __shared__ float Bsl[LC][NST];  // 2 KB
  const int tid = threadIdx.x;
  const int b = blockIdx.x / NCHUNK;
  const int c = blockIdx.x % NCHUNK;
  const int l0 = c * LC;

  if (tid < 128) {  // 32 rows x 16 B-vals; 4 bf16 per thread
    int r = tid >> 2, q = tid & 3;
    uint2 v = *(const uint2*)(bc + ((size_t)(b * LSEQ + l0 + r)) * 32 + q * 4);
    Bsl[r][q * 4 + 0] = bf2f((ushort)(v.x & 0xffff));
    Bsl[r][q * 4 + 1] = bf2f((ushort)(v.x >> 16));
    Bsl[r][q * 4 + 2] = bf2f((ushort)(v.y & 0xffff));
    Bsl[r][q * 4 + 3] = bf2f((ushort)(v.y >> 16));
  }
  float Aa2[NST];  // -exp(A_log) * log2(e)
#pragma unroll
  for (int q = 0; q < 4; ++q) {
    float4 v = *(const float4*)(A_log + tid * NST + q * 4);
    Aa2[q * 4 + 0] = -LOG2E * __expf(v.x);
    Aa2[q * 4 + 1] = -LOG2E * __expf(v.y);
    Aa2[q * 4 + 2] = -LOG2E * __expf(v.z);
    Aa2[q * 4 + 3] = -LOG2E * __expf(v.w);
  }
  __syncthreads();

  float h[NST];
#pragma unroll
  for (int n = 0; n < NST; ++n) h[n] = 0.f;
  float sdt = 0.f;

  const size_t base = ((size_t)b * LSEQ + l0) * DMODEL + tid;
  ushort dtr[4], ur[4];
#pragma unroll
  for (int j = 0; j < 4; ++j) {
    dtr[j] = delta[base + (size_t)j * DMODEL];
    ur[j] = xc[base + (size_t)j * DMODEL];
  }
  for (int lb = 0; lb < LC / 4; ++lb) {
    ushort dtn[4], un[4];
    if (lb < LC / 4 - 1) {
      size_t nb = base + (size_t)(lb * 4 + 4) * DMODEL;
#pragma unroll
      for (int j = 0; j < 4; ++j) {
        dtn[j] = delta[nb + (size_t)j * DMODEL];
        un[j] = xc[nb + (size_t)j * DMODEL];
      }
    }
#pragma unroll
    for (int j = 0; j < 4; ++j) {
      int l = lb * 4 + j;
      float dt = h2f(dtr[j]);
      float dtu = dt * bf2f(ur[j]);
      sdt += dt;
      f32x4 B0 = *(const f32x4*)&Bsl[l][0];
      f32x4 B1 = *(const f32x4*)&Bsl[l][4];
      f32x4 B2 = *(const f32x4*)&Bsl[l][8];
      f32x4 B3 = *(const f32x4*)&Bsl[l][12];
      float Bv[NST] = {B0.x, B0.y, B0.z, B0.w, B1.x, B1.y, B1.z, B1.w,
                       B2.x, B2.y, B2.z, B2.w, B3.x, B3.y, B3.z, B3.w};
#pragma unroll
      for (int n = 0; n < NST; ++n) {
        float ab = __builtin_amdgcn_exp2f(dt * Aa2[n]);
        h[n] = fmaf(ab, h[n], dtu * Bv[n]);
      }
    }
#pragma unroll
    for (int j = 0; j < 4; ++j) {
      dtr[j] = dtn[j];
      ur[j] = un[j];
    }
  }

  const size_t ob = (((size_t)(b * NCHUNK + c)) * DMODEL + tid) * NST;
#pragma unroll
  for (int q = 0; q < 4; ++q) {
    float4 hv = {h[q * 4 + 0], h[q * 4 + 1], h[q * 4 + 2], h[q * 4 + 3]};
    *(float4*)(hout + ob + q * 4) = hv;
    float4 cv = {__builtin_amdgcn_exp2f(sdt * Aa2[q * 4 + 0]),
                 __builtin_amdgcn_exp2f(sdt * Aa2[q * 4 + 1]),
                 __builtin_amdgcn_exp2f(sdt * Aa2[q * 4 + 2]),
                 __builtin_amdgcn_exp2f(sdt * Aa2[q * 4 + 3])};
    *(float4*)(cumA + ob + q * 4) = cv;
  }
}

// ---------------------------------------------------------------------------
// Scan pass 2: sequential combine; in-place h_out -> h_in (fp32).
// ---------------------------------------------------------------------------
__global__ __launch_bounds__(256) void scan_combine(
    float* __restrict__ hstate, const float* __restrict__ cumA) {
  const int t = blockIdx.x * 256 + threadIdx.x;
  const int n = t & (NST - 1);
  const int dd = (t / NST) & (DMODEL - 1);
  const int b = t / (NST * DMODEL);
  float h = 0.f;
  for (int c = 0; c < NCHUNK; ++c) {
    size_t idx = (((size_t)(b * NCHUNK + c)) * DMODEL + dd) * NST + n;
    float ho = hstate[idx];
    float ca = cumA[idx];
    hstate[idx] = h;
    h = fmaf(ca, h, ho);
  }
}

// ---------------------------------------------------------------------------
// Scan pass 3: replay with h_in; y_pre = (y + u*D)*sz  (sz = pre-silu'd z),
// written bf16 in-place over sz.
// ---------------------------------------------------------------------------
__global__ __launch_bounds__(256, 8) void scan_pass3(
    const ushort* __restrict__ delta, const ushort* __restrict__ xc,
    const ushort* __restrict__ bc, const float* __restrict__ A_log,
    const float* __restrict__ hin, const float* __restrict__ Dskip,
    ushort* __restrict__ zy) {
  __shared__ float BCs[LC][32];  // 4 KB
  const int tid = threadIdx.x;
  const int b = blockIdx.x / NCHUNK;
  const int c = blockIdx.x % NCHUNK;
  const int l0 = c * LC;

  {  // 32 rows x 32 vals; 4 bf16 per thread
    int r = tid >> 3, q = tid & 7;
    uint2 v = *(const uint2*)(bc + ((size_t)(b * LSEQ + l0 + r)) * 32 + q * 4);
    BCs[r][q * 4 + 0] = bf2f((ushort)(v.x & 0xffff));
    BCs[r][q * 4 + 1] = bf2f((ushort)(v.x >> 16));
    BCs[r][q * 4 + 2] = bf2f((ushort)(v.y & 0xffff));
    BCs[r][q * 4 + 3] = bf2f((ushort)(v.y >> 16));
  }
  float Aa2[NST];
#pragma unroll
  for (int q = 0; q < 4; ++q) {
    float4 v = *(const float4*)(A_log + tid * NST + q * 4);
    Aa2[q * 4 + 0] = -LOG2E * __expf(v.x);
    Aa2[q * 4 + 1] = -LOG2E * __expf(v.y);
    Aa2[q * 4 + 2] = -LOG2E * __expf(v.z);
    Aa2[q * 4 + 3] = -LOG2E * __expf(v.w);
  }
  float h[NST];
  const size_t hb = (((size_t)(b * NCHUNK + c)) * DMODEL + tid) * NST;
#pragma unroll
  for (int q = 0; q < 4; ++q) {
    float4 v = *(const float4*)(hin + hb + q * 4);
    h[q * 4 + 0] = v.x;
    h[q * 4 + 1] = v.y;
    h[q * 4 + 2] = v.z;
    h[q * 4 + 3] = v.w;
  }
  const float dsk = Dskip[tid];
  __syncthreads();

  const size_t base = ((size_t)b * LSEQ + l0) * DMODEL + tid;
  ushort dtr[4], ur[4], zr[4];
#pragma unroll
  for (int j = 0; j < 4; ++j) {
    dtr[j] = delta[base + (size_t)j * DMODEL];
    ur[j] = xc[base + (size_t)j * DMODEL];
    zr[j] = zy[base + (size_t)j * DMODEL];
  }
  for (int lb = 0; lb < LC / 4; ++lb) {
    ushort dtn[4], un[4], zn[4];
    if (lb < LC / 4 - 1) {
      size_t nb = base + (size_t)(lb * 4 + 4) * DMODEL;
#pragma unroll
      for (int j = 0; j < 4; ++j) {
        dtn[j] = delta[nb + (size_t)j * DMODEL];
        un[j] = xc[nb + (size_t)j * DMODEL];
        zn[j] = zy[nb + (size_t)j * DMODEL];
      }
    }
#pragma unroll
    for (int j = 0; j < 4; ++j) {
      int l = lb * 4 + j;
      float dt = h2f(dtr[j]);
      float u = bf2f(ur[j]);
      float dtu = dt * u;
      f32x4 B0 = *(const f32x4*)&BCs[l][0];
      f32x4 B1 = *(const f32x4*)&BCs[l][4];
      f32x4 B2 = *(const f32x4*)&BCs[l][8];
      f32x4 B3 = *(const f32x4*)&BCs[l][12];
      f32x4 C0 = *(const f32x4*)&BCs[l][16];
      f32x4 C1 = *(const f32x4*)&BCs[l][20];
      f32x4 C2 = *(const f32x4*)&BCs[l][24];
      f32x4 C3 = *(const f32x4*)&BCs[l][28];
      float Bv[NST] = {B0.x, B0.y, B0.z, B0.w, B1.x, B1.y, B1.z, B1.w,
                       B2.x, B2.y, B2.z, B2.w, B3.x, B3.y, B3.z, B3.w};
      float Cv[NST] = {C0.x, C0.y, C0.z, C0.w, C1.x, C1.y, C1.z, C1.w,
                       C2.x, C2.y, C2.z, C2.w, C3.x, C3.y, C3.z, C3.w};
      float y = 0.f;
#pragma unroll
      for (int n = 0; n < NST; ++n) {
        float ab = __builtin_amdgcn_exp2f(dt * Aa2[n]);
        h[n] = fmaf(ab, h[n], dtu * Bv[n]);
        y = fmaf(h[n], Cv[n], y);
      }
      size_t idx = base + (size_t)l * DMODEL;
      zy[idx] = (ushort)bf16rne((y + u * dsk) * bf2f(zr[j]));
    }
#pragma unroll
    for (int j = 0; j < 4; ++j) {
      dtr[j] = dtn[j];
      ur[j] = un[j];
      zr[j] = zn[j];
    }
  }
}

// ---------------------------------------------------------------------------
extern "C" void kernel_launch(void* const* d_in, const int* in_sizes, int n_in,
                              void* d_out, int out_size, void* d_ws,
                              size_t ws_size, hipStream_t stream) {
  const float* x       = (const float*)d_in[0];
  const float* A_log   = (const float*)d_in[1];
  const float* D_skip  = (const float*)d_in[2];
  const float* W_B     = (const float*)d_in[3];
  const float* W_C     = (const float*)d_in[4];
  const float* W_delta = (const float*)d_in[5];
  const float* b_delta = (const float*)d_in[6];
  const float* W_in    = (const float*)d_in[7];
  const float* b_in    = (const float*)d_in[8];
  const float* W_out   = (const float*)d_in[9];
  const float* b_out   = (const float*)d_in[10];
  const float* conv_w  = (const float*)d_in[11];
  const float* conv_b  = (const float*)d_in[12];

  const size_t MD = (size_t)MROWS * DMODEL;                 // 16.78M
  const size_t HP = (size_t)BATCH * NCHUNK * DMODEL * NST;  // 8.39M
  float* xin   = (float*)d_ws;              // x_in fp32 [MD]
  ushort* dl   = (ushort*)(xin + MD);       // delta fp16 [MD]
  ushort* szy  = dl + MD;                   // silu(z) bf16 -> y_pre bf16 [MD]
  ushort* xcb  = szy + MD;                  // xc bf16 [MD]
  ushort* bcb  = xcb + MD;                  // bc bf16 [MROWS*32]
  float* hst   = (float*)(bcb + (size_t)MROWS * 32);  // h_out -> h_in [HP]
  float* cumA  = hst + HP;                  // [HP]
  ushort* wbf  = (ushort*)(cumA + HP);      // bf16 weights, 270336
  // bytes: 67.1 + 33.6 + 33.6 + 33.6 + 4.2 + 33.6 + 33.6 + 0.5 ≈ 240 MB

  cvt_weights<<<dim3(132), 256, 0, stream>>>(W_in, W_delta, W_out, W_B, W_C, wbf);
  // 1) xz GEMM: x_in fp32 + silu(z) bf16
  gemm2<0><<<dim3(2, MROWS / 64), 256, 0, stream>>>(x, wbf, b_in, xin, szy);
  // 2) conv + silu -> xc bf16
  conv_silu_k<<<dim3(MROWS / 8), 256, 0, stream>>>(xin, conv_w, conv_b, xcb);
  // 3) delta fp16
  gemm2<1><<<dim3(1, MROWS / 64), 256, 0, stream>>>(xcb, wbf + 131072, b_delta, dl, nullptr);
  // 4) B/C bf16
  gemm_bc2<<<dim3(MROWS / 128), 256, 0, stream>>>(xcb, wbf + 262144, bcb);
  // 5) chunked scan (LC=32, 2048 blocks)
  scan_pass1<<<dim3(BATCH * NCHUNK), 256, 0, stream>>>(dl, xcb, bcb, A_log, hst, cumA);
  scan_combine<<<dim3(BATCH * DMODEL * NST / 256), 256, 0, stream>>>(hst, cumA);
  scan_pass3<<<dim3(BATCH * NCHUNK), 256, 0, stream>>>(dl, xcb, bcb, A_log, hst, D_skip, szy);
  // 6) out = y_pre @ W_out.T + b_out (fp32)
  gemm2<3><<<dim3(1, MROWS / 64), 256, 0, stream>>>(szy, wbf + 196608, b_out, d_out, nullptr);
}

// Round 6
// 260.832 us; speedup vs baseline: 1.2309x; 1.2309x over previous
//
#include <hip/hip_runtime.h>
#include <hip/hip_bf16.h>
#include <math.h>

#define BATCH 16
#define LSEQ 4096
#define DMODEL 256
#define NST 16
#define LC 64
#define NCHUNK (LSEQ / LC)    // 64
#define MROWS (BATCH * LSEQ)  // 65536
#define LOG2E 1.44269504088896340736f

typedef float f32x4 __attribute__((ext_vector_type(4)));
typedef short bf16x8 __attribute__((ext_vector_type(8)));

__device__ __forceinline__ float silu_f(float v) { return v / (1.f + __expf(-v)); }
__device__ __forceinline__ float softplus_f(float v) {
  return fmaxf(v, 0.f) + log1pf(__expf(-fabsf(v)));
}
__device__ __forceinline__ uint bf16rne(float f) {
  uint u = __float_as_uint(f);
  return (u + 0x7fffu + ((u >> 16) & 1u)) >> 16;
}
__device__ __forceinline__ float bf2f(ushort u) {
  return __uint_as_float((uint)u << 16);
}
__device__ __forceinline__ ushort f2h(float v) {
  _Float16 h = (_Float16)v;
  return __builtin_bit_cast(ushort, h);
}
__device__ __forceinline__ float h2f(ushort u) {
  return (float)__builtin_bit_cast(_Float16, u);
}
__device__ __forceinline__ uint pk2(float x, float y) {
  return bf16rne(x) | (bf16rne(y) << 16);
}
__device__ __forceinline__ uint4 pk8(float4 a, float4 b) {
  uint4 r;
  r.x = pk2(a.x, a.y);
  r.y = pk2(a.z, a.w);
  r.z = pk2(b.x, b.y);
  r.w = pk2(b.z, b.w);
  return r;
}

// async global(bf16)->LDS, 16 B per lane (dest = wave-uniform base + lane*16)
__device__ __forceinline__ void glds16(const ushort* g, char* l) {
  __builtin_amdgcn_global_load_lds(
      (const __attribute__((address_space(1))) void*)g,
      (__attribute__((address_space(3))) void*)l, 16, 0, 0);
}

// ---------------------------------------------------------------------------
// Weight fp32->bf16 convert. dst layout (ushort offsets):
//   [0,131072) W_in | [131072,196608) W_delta | [196608,262144) W_out
//   [262144,266240) W_B | [266240,270336) W_C
// ---------------------------------------------------------------------------
__global__ __launch_bounds__(256) void cvt_weights(
    const float* __restrict__ Win, const float* __restrict__ Wd,
    const float* __restrict__ Wo, const float* __restrict__ WB,
    const float* __restrict__ WC, ushort* __restrict__ dst) {
  size_t i = ((size_t)blockIdx.x * 256 + threadIdx.x) * 8;
  if (i >= 270336) return;
  const float* s;
  size_t o;
  if (i < 131072)      { s = Win; o = i; }
  else if (i < 196608) { s = Wd;  o = i - 131072; }
  else if (i < 262144) { s = Wo;  o = i - 196608; }
  else if (i < 266240) { s = WB;  o = i - 262144; }
  else                 { s = WC;  o = i - 266240; }
  float4 a = *(const float4*)(s + o);
  float4 b = *(const float4*)(s + o + 4);
  *(uint4*)(dst + i) = pk8(a, b);
}

// ---------------------------------------------------------------------------
// MODE0 GEMM (unchanged from R5): xz = x @ W_in^T + b_in.
// Tile 64x256, grid (2, M/64); col<256 -> x_in fp32, col>=256 -> silu(z) bf16.
// ---------------------------------------------------------------------------
__global__ __launch_bounds__(256, 4) void gemm_in(
    const float* __restrict__ A, const ushort* __restrict__ Bbf,
    const float* __restrict__ bias, float* __restrict__ out0,
    ushort* __restrict__ out1) {
  constexpr int KD = 256;
  __shared__ char smem[40960];  // buf stride 20480: A 4KB @0, B 16KB @4096
  const int tid = threadIdx.x;
  const int lane = tid & 63, wid = tid >> 6;
  const int M0 = blockIdx.y * 64;
  const int N0 = blockIdx.x * 256;

  const int rA = tid >> 2, cA = tid & 3;
  const int sA = (rA + (rA >> 2)) & 3;
  const int ldsAoff = rA * 64 + ((cA ^ sA) * 16);
  const float* gA32 = A + (size_t)(M0 + rA) * KD + cA * 8;
  const ushort* gB = Bbf + (size_t)(N0 + rA) * KD + ((cA ^ sA) * 8);

  f32x4 acc[4][4];
#pragma unroll
  for (int i = 0; i < 4; ++i)
#pragma unroll
    for (int j = 0; j < 4; ++j) acc[i][j] = {0.f, 0.f, 0.f, 0.f};

  {
#pragma unroll
    for (int i = 0; i < 4; ++i)
      glds16(gB + (size_t)i * 64 * KD, smem + 4096 + i * 4096 + wid * 1024);
    float4 a0 = *(const float4*)(gA32);
    float4 a1 = *(const float4*)(gA32 + 4);
    *(uint4*)(smem + ldsAoff) = pk8(a0, a1);
  }
  __syncthreads();

  for (int step = 0; step < 8; ++step) {
    const int cur = step & 1;
    char* bufc = smem + cur * 20480;
    char* bufn = smem + (cur ^ 1) * 20480;
    float4 na0, na1;
    if (step < 7) {
      const int k0 = (step + 1) * 32;
#pragma unroll
      for (int i = 0; i < 4; ++i)
        glds16(gB + (size_t)i * 64 * KD + k0,
               bufn + 4096 + i * 4096 + wid * 1024);
      na0 = *(const float4*)(gA32 + k0);
      na1 = *(const float4*)(gA32 + k0 + 4);
    }
    bf16x8 af[4], bfr[4];
#pragma unroll
    for (int i = 0; i < 4; ++i) {
      int r = i * 16 + (lane & 15);
      int slot = (lane >> 4) ^ ((r + (r >> 2)) & 3);
      af[i] = *(const bf16x8*)(bufc + r * 64 + slot * 16);
    }
#pragma unroll
    for (int j = 0; j < 4; ++j) {
      int r = wid * 64 + j * 16 + (lane & 15);
      int slot = (lane >> 4) ^ ((r + (r >> 2)) & 3);
      bfr[j] = *(const bf16x8*)(bufc + 4096 + r * 64 + slot * 16);
    }
#pragma unroll
    for (int i = 0; i < 4; ++i)
#pragma unroll
      for (int j = 0; j < 4; ++j)
        acc[i][j] = __builtin_amdgcn_mfma_f32_16x16x32_bf16(af[i], bfr[j],
                                                            acc[i][j], 0, 0, 0);
    if (step < 7) *(uint4*)(bufn + ldsAoff) = pk8(na0, na1);
    __syncthreads();
  }

  const int rbase = (lane >> 4) * 4;
  const int cn = lane & 15;
#pragma unroll
  for (int i = 0; i < 4; ++i) {
#pragma unroll
    for (int j = 0; j < 4; ++j) {
      int col = N0 + wid * 64 + j * 16 + cn;
      float bs = bias[col];
#pragma unroll
      for (int r = 0; r < 4; ++r) {
        int row = M0 + i * 16 + rbase + r;
        float v = acc[i][j][r] + bs;
        if (col < DMODEL)
          out0[(size_t)row * DMODEL + col] = v;
        else
          out1[(size_t)row * DMODEL + (col - DMODEL)] = (ushort)bf16rne(silu_f(v));
      }
    }
  }
}

// ---------------------------------------------------------------------------
// K2 fused_mid: conv+silu -> xc (LDS tile + global), delta GEMM (softplus,
// fp16 out), BC GEMM, scan pass1 -> hout/cumA. Block = (b, 64-l chunk).
// LDS: @0 xc bf16 [64 rows][32 chunks] swz c^(r&7)      (32 KB)
//      @32768 B dbuf 16KB x2 -> later delta fp16 [64][256] plain (32 KB)
//      @65536 WBC bf16 [32][32c] swz -> later BC f32 [64][32]    (16 KB)
// ---------------------------------------------------------------------------
__global__ __launch_bounds__(256, 2) void fused_mid(
    const float* __restrict__ xin, const ushort* __restrict__ wdl,
    const ushort* __restrict__ wbc, const float* __restrict__ b_delta,
    const float* __restrict__ A_log, const float* __restrict__ conv_w,
    const float* __restrict__ conv_b, ushort* __restrict__ xc_g,
    ushort* __restrict__ dl_g, ushort* __restrict__ bc_g,
    float* __restrict__ hout, float* __restrict__ cumA) {
  __shared__ char smem[81920];
  const int tid = threadIdx.x, lane = tid & 63, wid = tid >> 6;
  const int b = blockIdx.x / NCHUNK, c = blockIdx.x % NCHUNK;
  const int l0 = c * LC;
  const size_t row0 = (size_t)b * LSEQ + l0;

  // ---- issue WBC staging (whole 32x256) early
  {
    const int rB = tid >> 5, cB = tid & 31;
    const ushort* gW = wbc + (size_t)rB * 256 + ((cB ^ (rB & 7)) * 8);
#pragma unroll
    for (int i = 0; i < 4; ++i)
      glds16(gW + (size_t)(8 * i) * 256, smem + 65536 + (8 * i + 2 * wid) * 512);
  }
  // ---- issue W_delta k-step 0
  const int rB4 = tid >> 2, cB4 = tid & 3;
  const int sB4 = (rB4 + (rB4 >> 2)) & 3;
  const ushort* gB = wdl + (size_t)rB4 * 256 + ((cB4 ^ sB4) * 8);
#pragma unroll
  for (int i = 0; i < 4; ++i)
    glds16(gB + (size_t)i * 64 * 256, smem + 32768 + i * 4096 + wid * 1024);

  // ---- conv + silu -> xc tile (LDS swizzled) + xc global
  {
    const int dq = tid & 31;
    const int d0 = dq * 8;
    float w0[8], w1[8], w2[8], cb[8];
#pragma unroll
    for (int k = 0; k < 8; ++k) {
      w0[k] = conv_w[(d0 + k) * 3 + 0];
      w1[k] = conv_w[(d0 + k) * 3 + 1];
      w2[k] = conv_w[(d0 + k) * 3 + 2];
      cb[k] = conv_b[d0 + k];
    }
#pragma unroll
    for (int it = 0; it < 8; ++it) {
      const int lr = it * 8 + (tid >> 5);
      const int l = l0 + lr;
      const size_t bp = (row0 + lr) * DMODEL + d0;
      float4 zf = {0.f, 0.f, 0.f, 0.f};
      float4 m0 = zf, m1 = zf, p0 = zf, p1 = zf;
      if (l > 0) {
        m0 = *(const float4*)(xin + bp - DMODEL);
        m1 = *(const float4*)(xin + bp - DMODEL + 4);
      }
      float4 c0 = *(const float4*)(xin + bp);
      float4 c1 = *(const float4*)(xin + bp + 4);
      if (l < LSEQ - 1) {
        p0 = *(const float4*)(xin + bp + DMODEL);
        p1 = *(const float4*)(xin + bp + DMODEL + 4);
      }
      float mv[8] = {m0.x, m0.y, m0.z, m0.w, m1.x, m1.y, m1.z, m1.w};
      float cv[8] = {c0.x, c0.y, c0.z, c0.w, c1.x, c1.y, c1.z, c1.w};
      float pv[8] = {p0.x, p0.y, p0.z, p0.w, p1.x, p1.y, p1.z, p1.w};
      float ov[8];
#pragma unroll
      for (int k = 0; k < 8; ++k) {
        float o = fmaf(w0[k], mv[k], fmaf(w1[k], cv[k], fmaf(w2[k], pv[k], cb[k])));
        ov[k] = silu_f(o);
      }
      uint4 r4;
      r4.x = pk2(ov[0], ov[1]);
      r4.y = pk2(ov[2], ov[3]);
      r4.z = pk2(ov[4], ov[5]);
      r4.w = pk2(ov[6], ov[7]);
      *(uint4*)(xc_g + bp) = r4;
      *(uint4*)(smem + lr * 512 + ((dq ^ (lr & 7)) * 16)) = r4;
    }
  }
  __syncthreads();  // xc tile + WBC + B-k0 ready

  // ---- delta GEMM: A = xc tile (full-A in LDS), B = W_delta streamed
  f32x4 acc[4][4];
#pragma unroll
  for (int i = 0; i < 4; ++i)
#pragma unroll
    for (int j = 0; j < 4; ++j) acc[i][j] = {0.f, 0.f, 0.f, 0.f};

  for (int step = 0; step < 8; ++step) {
    char* bufc = smem + 32768 + (step & 1) * 16384;
    if (step < 7) {
      char* bufn = smem + 32768 + ((step + 1) & 1) * 16384;
      const int k0 = (step + 1) * 32;
#pragma unroll
      for (int i = 0; i < 4; ++i)
        glds16(gB + (size_t)i * 64 * 256 + k0, bufn + i * 4096 + wid * 1024);
    }
    bf16x8 af[4], bfr[4];
#pragma unroll
    for (int i = 0; i < 4; ++i) {
      int r = i * 16 + (lane & 15);
      int sc = step * 4 + (lane >> 4);
      af[i] = *(const bf16x8*)(smem + r * 512 + ((sc ^ (r & 7)) * 16));
    }
#pragma unroll
    for (int j = 0; j < 4; ++j) {
      int r = wid * 64 + j * 16 + (lane & 15);
      int slot = (lane >> 4) ^ ((r + (r >> 2)) & 3);
      bfr[j] = *(const bf16x8*)(bufc + r * 64 + slot * 16);
    }
#pragma unroll
    for (int i = 0; i < 4; ++i)
#pragma unroll
      for (int j = 0; j < 4; ++j)
        acc[i][j] = __builtin_amdgcn_mfma_f32_16x16x32_bf16(af[i], bfr[j],
                                                            acc[i][j], 0, 0, 0);
    __syncthreads();
  }

  // ---- BC GEMM (pure LDS: xc tile x WBC), 16 rows/wave x 32 cols
  f32x4 accbc[2];
  accbc[0] = {0.f, 0.f, 0.f, 0.f};
  accbc[1] = {0.f, 0.f, 0.f, 0.f};
#pragma unroll
  for (int step = 0; step < 8; ++step) {
    int sc = step * 4 + (lane >> 4);
    int ra = wid * 16 + (lane & 15);
    bf16x8 a2 = *(const bf16x8*)(smem + ra * 512 + ((sc ^ (ra & 7)) * 16));
#pragma unroll
    for (int j = 0; j < 2; ++j) {
      int br = j * 16 + (lane & 15);
      bf16x8 b2 = *(const bf16x8*)(smem + 65536 + br * 512 + ((sc ^ (br & 7)) * 16));
      accbc[j] = __builtin_amdgcn_mfma_f32_16x16x32_bf16(a2, b2, accbc[j], 0, 0, 0);
    }
  }

  // ---- delta epilogue -> dtile fp16 [64][256] plain @32768
  const int rbase = (lane >> 4) * 4;
  const int cn = lane & 15;
#pragma unroll
  for (int i = 0; i < 4; ++i)
#pragma unroll
    for (int j = 0; j < 4; ++j) {
      int col = wid * 64 + j * 16 + cn;
      float bs = b_delta[col];
#pragma unroll
      for (int r = 0; r < 4; ++r) {
        int row = i * 16 + rbase + r;
        *(ushort*)(smem + 32768 + row * 512 + col * 2) =
            f2h(softplus_f(acc[i][j][r] + bs));
      }
    }
  __syncthreads();  // WBC reads + dtile writes done

  // ---- BC epilogue: BC f32 tile @65536 (over WBC) + bc_g global (bf16)
#pragma unroll
  for (int j = 0; j < 2; ++j)
#pragma unroll
    for (int r = 0; r < 4; ++r) {
      int row = wid * 16 + rbase + r;
      int col = j * 16 + cn;
      ushort bv = (ushort)bf16rne(accbc[j][r]);
      ((float*)(smem + 65536))[row * 32 + col] = bf2f(bv);
      bc_g[(row0 + row) * 32 + col] = bv;
    }
  // ---- dl_g coalesced write from dtile
#pragma unroll
  for (int it = 0; it < 8; ++it) {
    int idx = it * 256 + tid;
    int row = idx >> 5, ch = idx & 31;
    *(uint4*)(dl_g + (row0 + row) * DMODEL + ch * 8) =
        *(const uint4*)(smem + 32768 + idx * 16);
  }
  __syncthreads();  // BC f32 visible

  // ---- scan pass1 (all inputs in LDS)
  float Aa2[NST];
#pragma unroll
  for (int q = 0; q < 4; ++q) {
    float4 v = *(const float4*)(A_log + tid * NST + q * 4);
    Aa2[q * 4 + 0] = -LOG2E * __expf(v.x);
    Aa2[q * 4 + 1] = -LOG2E * __expf(v.y);
    Aa2[q * 4 + 2] = -LOG2E * __expf(v.z);
    Aa2[q * 4 + 3] = -LOG2E * __expf(v.w);
  }
  float h[NST];
#pragma unroll
  for (int n = 0; n < NST; ++n) h[n] = 0.f;
  float sdt = 0.f;
  const int uoff0 = (tid & 7) * 2;
  const int uchunk = tid >> 3;
#pragma unroll 4
  for (int l = 0; l < LC; ++l) {
    float dt = h2f(*(const ushort*)(smem + 32768 + l * 512 + tid * 2));
    float u = bf2f(*(const ushort*)(smem + l * 512 +
                                    ((uchunk ^ (l & 7)) * 16) + uoff0));
    sdt += dt;
    float dtu = dt * u;
    const float* Bp = (const float*)(smem + 65536) + l * 32;
    f32x4 B0 = *(const f32x4*)(Bp);
    f32x4 B1 = *(const f32x4*)(Bp + 4);
    f32x4 B2 = *(const f32x4*)(Bp + 8);
    f32x4 B3 = *(const f32x4*)(Bp + 12);
    float Bv[NST] = {B0.x, B0.y, B0.z, B0.w, B1.x, B1.y, B1.z, B1.w,
                     B2.x, B2.y, B2.z, B2.w, B3.x, B3.y, B3.z, B3.w};
#pragma unroll
    for (int n = 0; n < NST; ++n) {
      float ab = __builtin_amdgcn_exp2f(dt * Aa2[n]);
      h[n] = fmaf(ab, h[n], dtu * Bv[n]);
    }
  }
  const size_t ob = (((size_t)(b * NCHUNK + c)) * DMODEL + tid) * NST;
#pragma unroll
  for (int q = 0; q < 4; ++q) {
    float4 hv = {h[q * 4 + 0], h[q * 4 + 1], h[q * 4 + 2], h[q * 4 + 3]};
    *(float4*)(hout + ob + q * 4) = hv;
    float4 cvv = {__builtin_amdgcn_exp2f(sdt * Aa2[q * 4 + 0]),
                  __builtin_amdgcn_exp2f(sdt * Aa2[q * 4 + 1]),
                  __builtin_amdgcn_exp2f(sdt * Aa2[q * 4 + 2]),
                  __builtin_amdgcn_exp2f(sdt * Aa2[q * 4 + 3])};
    *(float4*)(cumA + ob + q * 4) = cvv;
  }
}

// ---------------------------------------------------------------------------
// Scan combine: sequential over chunks; in-place h_out -> h_in (fp32).
// ---------------------------------------------------------------------------
__global__ __launch_bounds__(256) void scan_combine(
    float* __restrict__ hstate, const float* __restrict__ cumA) {
  const int t = blockIdx.x * 256 + threadIdx.x;
  const int n = t & (NST - 1);
  const int dd = (t / NST) & (DMODEL - 1);
  const int b = t / (NST * DMODEL);
  float h = 0.f;
  for (int c = 0; c < NCHUNK; ++c) {
    size_t idx = (((size_t)(b * NCHUNK + c)) * DMODEL + dd) * NST + n;
    float ho = hstate[idx];
    float ca = cumA[idx];
    hstate[idx] = h;
    h = fmaf(ca, h, ho);
  }
}

// ---------------------------------------------------------------------------
// K3 fused_out: scan pass3 -> y_pre LDS tile -> GEMM with W_out -> d_out.
// LDS: @0 ypre bf16 [64][32c] swz c^(r&7) (32 KB); @32768 B dbuf 16KBx2;
//      @65536 BC f32 [64][32] (8 KB).
// ---------------------------------------------------------------------------
__global__ __launch_bounds__(256, 2) void fused_out(
    const ushort* __restrict__ dl, const ushort* __restrict__ xcb,
    const ushort* __restrict__ szy, const ushort* __restrict__ bcb,
    const float* __restrict__ A_log, const float* __restrict__ hin,
    const float* __restrict__ Dskip, const ushort* __restrict__ wout,
    const float* __restrict__ b_out, float* __restrict__ out) {
  __shared__ char smem[73728];
  const int tid = threadIdx.x, lane = tid & 63, wid = tid >> 6;
  const int b = blockIdx.x / NCHUNK, c = blockIdx.x % NCHUNK;
  const int l0 = c * LC;
  const size_t row0 = (size_t)b * LSEQ + l0;

  // stage BC f32 tile
#pragma unroll
  for (int i = 0; i < 2; ++i) {
    int t = tid + i * 256;
    int r = t >> 3, q = t & 7;
    uint2 v = *(const uint2*)(bcb + (row0 + r) * 32 + q * 4);
    float* dp = (float*)(smem + 65536) + r * 32 + q * 4;
    dp[0] = bf2f((ushort)(v.x & 0xffff));
    dp[1] = bf2f((ushort)(v.x >> 16));
    dp[2] = bf2f((ushort)(v.y & 0xffff));
    dp[3] = bf2f((ushort)(v.y >> 16));
  }
  // issue W_out k-step 0
  const int rB4 = tid >> 2, cB4 = tid & 3;
  const int sB4 = (rB4 + (rB4 >> 2)) & 3;
  const ushort* gB = wout + (size_t)rB4 * 256 + ((cB4 ^ sB4) * 8);
#pragma unroll
  for (int i = 0; i < 4; ++i)
    glds16(gB + (size_t)i * 64 * 256, smem + 32768 + i * 4096 + wid * 1024);

  float Aa2[NST];
#pragma unroll
  for (int q = 0; q < 4; ++q) {
    float4 v = *(const float4*)(A_log + tid * NST + q * 4);
    Aa2[q * 4 + 0] = -LOG2E * __expf(v.x);
    Aa2[q * 4 + 1] = -LOG2E * __expf(v.y);
    Aa2[q * 4 + 2] = -LOG2E * __expf(v.z);
    Aa2[q * 4 + 3] = -LOG2E * __expf(v.w);
  }
  float h[NST];
  const size_t hb = (((size_t)(b * NCHUNK + c)) * DMODEL + tid) * NST;
#pragma unroll
  for (int q = 0; q < 4; ++q) {
    float4 v = *(const float4*)(hin + hb + q * 4);
    h[q * 4 + 0] = v.x;
    h[q * 4 + 1] = v.y;
    h[q * 4 + 2] = v.z;
    h[q * 4 + 3] = v.w;
  }
  const float dsk = Dskip[tid];
  __syncthreads();  // BC tile ready

  // ---- scan (global scalar reads w/ rolling prefetch), y_pre -> LDS
  const size_t base = row0 * DMODEL + tid;
  const int ywoff = (tid & 7) * 2;
  const int ywchunk = tid >> 3;
  ushort dtr[4], ur[4], zr[4];
#pragma unroll
  for (int j = 0; j < 4; ++j) {
    dtr[j] = dl[base + (size_t)j * DMODEL];
    ur[j] = xcb[base + (size_t)j * DMODEL];
    zr[j] = szy[base + (size_t)j * DMODEL];
  }
  for (int lb = 0; lb < LC / 4; ++lb) {
    ushort dtn[4], un[4], zn[4];
    if (lb < LC / 4 - 1) {
      size_t nb = base + (size_t)(lb * 4 + 4) * DMODEL;
#pragma unroll
      for (int j = 0; j < 4; ++j) {
        dtn[j] = dl[nb + (size_t)j * DMODEL];
        un[j] = xcb[nb + (size_t)j * DMODEL];
        zn[j] = szy[nb + (size_t)j * DMODEL];
      }
    }
#pragma unroll
    for (int j = 0; j < 4; ++j) {
      int l = lb * 4 + j;
      float dt = h2f(dtr[j]);
      float u = bf2f(ur[j]);
      float dtu = dt * u;
      const float* Bp = (const float*)(smem + 65536) + l * 32;
      f32x4 B0 = *(const f32x4*)(Bp);
      f32x4 B1 = *(const f32x4*)(Bp + 4);
      f32x4 B2 = *(const f32x4*)(Bp + 8);
      f32x4 B3 = *(const f32x4*)(Bp + 12);
      f32x4 C0 = *(const f32x4*)(Bp + 16);
      f32x4 C1 = *(const f32x4*)(Bp + 20);
      f32x4 C2 = *(const f32x4*)(Bp + 24);
      f32x4 C3 = *(const f32x4*)(Bp + 28);
      float Bv[NST] = {B0.x, B0.y, B0.z, B0.w, B1.x, B1.y, B1.z, B1.w,
                       B2.x, B2.y, B2.z, B2.w, B3.x, B3.y, B3.z, B3.w};
      float Cv[NST] = {C0.x, C0.y, C0.z, C0.w, C1.x, C1.y, C1.z, C1.w,
                       C2.x, C2.y, C2.z, C2.w, C3.x, C3.y, C3.z, C3.w};
      float y = 0.f;
#pragma unroll
      for (int n = 0; n < NST; ++n) {
        float ab = __builtin_amdgcn_exp2f(dt * Aa2[n]);
        h[n] = fmaf(ab, h[n], dtu * Bv[n]);
        y = fmaf(h[n], Cv[n], y);
      }
      float yp = (y + u * dsk) * bf2f(zr[j]);
      *(ushort*)(smem + l * 512 + ((ywchunk ^ (l & 7)) * 16) + ywoff) =
          (ushort)bf16rne(yp);
    }
#pragma unroll
    for (int j = 0; j < 4; ++j) {
      dtr[j] = dtn[j];
      ur[j] = un[j];
      zr[j] = zn[j];
    }
  }
  __syncthreads();  // ypre tile complete

  // ---- output GEMM: A = ypre tile, B = W_out streamed
  f32x4 acc[4][4];
#pragma unroll
  for (int i = 0; i < 4; ++i)
#pragma unroll
    for (int j = 0; j < 4; ++j) acc[i][j] = {0.f, 0.f, 0.f, 0.f};

  for (int step = 0; step < 8; ++step) {
    char* bufc = smem + 32768 + (step & 1) * 16384;
    if (step < 7) {
      char* bufn = smem + 32768 + ((step + 1) & 1) * 16384;
      const int k0 = (step + 1) * 32;
#pragma unroll
      for (int i = 0; i < 4; ++i)
        glds16(gB + (size_t)i * 64 * 256 + k0, bufn + i * 4096 + wid * 1024);
    }
    bf16x8 af[4], bfr[4];
#pragma unroll
    for (int i = 0; i < 4; ++i) {
      int r = i * 16 + (lane & 15);
      int sc = step * 4 + (lane >> 4);
      af[i] = *(const bf16x8*)(smem + r * 512 + ((sc ^ (r & 7)) * 16));
    }
#pragma unroll
    for (int j = 0; j < 4; ++j) {
      int r = wid * 64 + j * 16 + (lane & 15);
      int slot = (lane >> 4) ^ ((r + (r >> 2)) & 3);
      bfr[j] = *(const bf16x8*)(bufc + r * 64 + slot * 16);
    }
#pragma unroll
    for (int i = 0; i < 4; ++i)
#pragma unroll
      for (int j = 0; j < 4; ++j)
        acc[i][j] = __builtin_amdgcn_mfma_f32_16x16x32_bf16(af[i], bfr[j],
                                                            acc[i][j], 0, 0, 0);
    __syncthreads();
  }

  const int rbase = (lane >> 4) * 4;
  const int cn = lane & 15;
#pragma unroll
  for (int i = 0; i < 4; ++i)
#pragma unroll
    for (int j = 0; j < 4; ++j) {
      int col = wid * 64 + j * 16 + cn;
      float bs = b_out[col];
#pragma unroll
      for (int r = 0; r < 4; ++r) {
        int row = i * 16 + rbase + r;
        out[(row0 + row) * DMODEL + col] = acc[i][j][r] + bs;
      }
    }
}

// ---------------------------------------------------------------------------
extern "C" void kernel_launch(void* const* d_in, const int* in_sizes, int n_in,
                              void* d_out, int out_size, void* d_ws,
                              size_t ws_size, hipStream_t stream) {
  const float* x       = (const float*)d_in[0];
  const float* A_log   = (const float*)d_in[1];
  const float* D_skip  = (const float*)d_in[2];
  const float* W_B     = (const float*)d_in[3];
  const float* W_C     = (const float*)d_in[4];
  const float* W_delta = (const float*)d_in[5];
  const float* b_delta = (const float*)d_in[6];
  const float* W_in    = (const float*)d_in[7];
  const float* b_in    = (const float*)d_in[8];
  const float* W_out   = (const float*)d_in[9];
  const float* b_out   = (const float*)d_in[10];
  const float* conv_w  = (const float*)d_in[11];
  const float* conv_b  = (const float*)d_in[12];

  const size_t MD = (size_t)MROWS * DMODEL;                 // 16.78M
  const size_t HP = (size_t)BATCH * NCHUNK * DMODEL * NST;  // 4.19M
  float* xin   = (float*)d_ws;              // x_in fp32 [MD]
  ushort* dl   = (ushort*)(xin + MD);       // delta fp16 [MD]
  ushort* szy  = dl + MD;                   // silu(z) bf16 [MD]
  ushort* xcb  = szy + MD;                  // xc bf16 [MD]
  ushort* bcb  = xcb + MD;                  // bc bf16 [MROWS*32]
  float* hst   = (float*)(bcb + (size_t)MROWS * 32);  // h_out -> h_in [HP]
  float* cumA  = hst + HP;                  // [HP]
  ushort* wbf  = (ushort*)(cumA + HP);      // bf16 weights, 270336

  cvt_weights<<<dim3(132), 256, 0, stream>>>(W_in, W_delta, W_out, W_B, W_C, wbf);
  gemm_in<<<dim3(2, MROWS / 64), 256, 0, stream>>>(x, wbf, b_in, xin, szy);
  fused_mid<<<dim3(BATCH * NCHUNK), 256, 0, stream>>>(
      xin, wbf + 131072, wbf + 262144, b_delta, A_log, conv_w, conv_b,
      xcb, dl, bcb, hst, cumA);
  scan_combine<<<dim3(BATCH * DMODEL * NST / 256), 256, 0, stream>>>(hst, cumA);
  fused_out<<<dim3(BATCH * NCHUNK), 256, 0, stream>>>(
      dl, xcb, szy, bcb, A_log, hst, D_skip, wbf + 196608, b_out,
      (float*)d_out);
}

// Round 7
// 245.389 us; speedup vs baseline: 1.3084x; 1.0629x over previous
//
#include <hip/hip_runtime.h>
#include <hip/hip_bf16.h>
#include <math.h>

#define BATCH 16
#define LSEQ 4096
#define DMODEL 256
#define NST 16
#define LC 64
#define NCHUNK (LSEQ / LC)    // 64
#define MROWS (BATCH * LSEQ)  // 65536
#define LOG2E 1.44269504088896340736f

typedef float f32x4 __attribute__((ext_vector_type(4)));
typedef short bf16x8 __attribute__((ext_vector_type(8)));

__device__ __forceinline__ float silu_f(float v) { return v / (1.f + __expf(-v)); }
__device__ __forceinline__ float softplus_f(float v) {
  return fmaxf(v, 0.f) + log1pf(__expf(-fabsf(v)));
}
__device__ __forceinline__ uint bf16rne(float f) {
  uint u = __float_as_uint(f);
  return (u + 0x7fffu + ((u >> 16) & 1u)) >> 16;
}
__device__ __forceinline__ float bf2f(ushort u) {
  return __uint_as_float((uint)u << 16);
}
__device__ __forceinline__ ushort f2h(float v) {
  _Float16 h = (_Float16)v;
  return __builtin_bit_cast(ushort, h);
}
__device__ __forceinline__ float h2f(ushort u) {
  return (float)__builtin_bit_cast(_Float16, u);
}
__device__ __forceinline__ uint pk2(float x, float y) {
  return bf16rne(x) | (bf16rne(y) << 16);
}
__device__ __forceinline__ uint4 pk8(float4 a, float4 b) {
  uint4 r;
  r.x = pk2(a.x, a.y);
  r.y = pk2(a.z, a.w);
  r.z = pk2(b.x, b.y);
  r.w = pk2(b.z, b.w);
  return r;
}

// p[n] = e1^(n+1), 15 muls, dep depth 4
__device__ __forceinline__ void pow16(float e1, float* p) {
  p[0] = e1;
  p[1] = e1 * e1;
  p[2] = p[1] * e1;
  p[3] = p[1] * p[1];
  p[4] = p[3] * e1;
  p[5] = p[3] * p[1];
  p[6] = p[3] * p[2];
  p[7] = p[3] * p[3];
  p[8] = p[7] * e1;
  p[9] = p[7] * p[1];
  p[10] = p[7] * p[2];
  p[11] = p[7] * p[3];
  p[12] = p[7] * p[4];
  p[13] = p[7] * p[5];
  p[14] = p[7] * p[6];
  p[15] = p[7] * p[7];
}

// async global(bf16)->LDS, 16 B per lane (dest = wave-uniform base + lane*16)
__device__ __forceinline__ void glds16(const ushort* g, char* l) {
  __builtin_amdgcn_global_load_lds(
      (const __attribute__((address_space(1))) void*)g,
      (__attribute__((address_space(3))) void*)l, 16, 0, 0);
}

// ---------------------------------------------------------------------------
// Weight fp32->bf16 convert. dst layout (ushort offsets):
//   [0,131072) W_in | [131072,196608) W_delta | [196608,262144) W_out
//   [262144,266240) W_B | [266240,270336) W_C
// ---------------------------------------------------------------------------
__global__ __launch_bounds__(256) void cvt_weights(
    const float* __restrict__ Win, const float* __restrict__ Wd,
    const float* __restrict__ Wo, const float* __restrict__ WB,
    const float* __restrict__ WC, ushort* __restrict__ dst) {
  size_t i = ((size_t)blockIdx.x * 256 + threadIdx.x) * 8;
  if (i >= 270336) return;
  const float* s;
  size_t o;
  if (i < 131072)      { s = Win; o = i; }
  else if (i < 196608) { s = Wd;  o = i - 131072; }
  else if (i < 262144) { s = Wo;  o = i - 196608; }
  else if (i < 266240) { s = WB;  o = i - 262144; }
  else                 { s = WC;  o = i - 266240; }
  float4 a = *(const float4*)(s + o);
  float4 b = *(const float4*)(s + o + 4);
  *(uint4*)(dst + i) = pk8(a, b);
}

// ---------------------------------------------------------------------------
// MODE0 GEMM: xz = x @ W_in^T + b_in. Tile 64x256, grid (2, M/64);
// col<256 -> x_in fp32, col>=256 -> silu(z) bf16.
// ---------------------------------------------------------------------------
__global__ __launch_bounds__(256, 4) void gemm_in(
    const float* __restrict__ A, const ushort* __restrict__ Bbf,
    const float* __restrict__ bias, float* __restrict__ out0,
    ushort* __restrict__ out1) {
  constexpr int KD = 256;
  __shared__ char smem[40960];  // buf stride 20480: A 4KB @0, B 16KB @4096
  const int tid = threadIdx.x;
  const int lane = tid & 63, wid = tid >> 6;
  const int M0 = blockIdx.y * 64;
  const int N0 = blockIdx.x * 256;

  const int rA = tid >> 2, cA = tid & 3;
  const int sA = (rA + (rA >> 2)) & 3;
  const int ldsAoff = rA * 64 + ((cA ^ sA) * 16);
  const float* gA32 = A + (size_t)(M0 + rA) * KD + cA * 8;
  const ushort* gB = Bbf + (size_t)(N0 + rA) * KD + ((cA ^ sA) * 8);

  f32x4 acc[4][4];
#pragma unroll
  for (int i = 0; i < 4; ++i)
#pragma unroll
    for (int j = 0; j < 4; ++j) acc[i][j] = {0.f, 0.f, 0.f, 0.f};

  {
#pragma unroll
    for (int i = 0; i < 4; ++i)
      glds16(gB + (size_t)i * 64 * KD, smem + 4096 + i * 4096 + wid * 1024);
    float4 a0 = *(const float4*)(gA32);
    float4 a1 = *(const float4*)(gA32 + 4);
    *(uint4*)(smem + ldsAoff) = pk8(a0, a1);
  }
  __syncthreads();

  for (int step = 0; step < 8; ++step) {
    const int cur = step & 1;
    char* bufc = smem + cur * 20480;
    char* bufn = smem + (cur ^ 1) * 20480;
    float4 na0, na1;
    if (step < 7) {
      const int k0 = (step + 1) * 32;
#pragma unroll
      for (int i = 0; i < 4; ++i)
        glds16(gB + (size_t)i * 64 * KD + k0,
               bufn + 4096 + i * 4096 + wid * 1024);
      na0 = *(const float4*)(gA32 + k0);
      na1 = *(const float4*)(gA32 + k0 + 4);
    }
    bf16x8 af[4], bfr[4];
#pragma unroll
    for (int i = 0; i < 4; ++i) {
      int r = i * 16 + (lane & 15);
      int slot = (lane >> 4) ^ ((r + (r >> 2)) & 3);
      af[i] = *(const bf16x8*)(bufc + r * 64 + slot * 16);
    }
#pragma unroll
    for (int j = 0; j < 4; ++j) {
      int r = wid * 64 + j * 16 + (lane & 15);
      int slot = (lane >> 4) ^ ((r + (r >> 2)) & 3);
      bfr[j] = *(const bf16x8*)(bufc + 4096 + r * 64 + slot * 16);
    }
#pragma unroll
    for (int i = 0; i < 4; ++i)
#pragma unroll
      for (int j = 0; j < 4; ++j)
        acc[i][j] = __builtin_amdgcn_mfma_f32_16x16x32_bf16(af[i], bfr[j],
                                                            acc[i][j], 0, 0, 0);
    if (step < 7) *(uint4*)(bufn + ldsAoff) = pk8(na0, na1);
    __syncthreads();
  }

  const int rbase = (lane >> 4) * 4;
  const int cn = lane & 15;
#pragma unroll
  for (int i = 0; i < 4; ++i) {
#pragma unroll
    for (int j = 0; j < 4; ++j) {
      int col = N0 + wid * 64 + j * 16 + cn;
      float bs = bias[col];
#pragma unroll
      for (int r = 0; r < 4; ++r) {
        int row = M0 + i * 16 + rbase + r;
        float v = acc[i][j][r] + bs;
        if (col < DMODEL)
          out0[(size_t)row * DMODEL + col] = v;
        else
          out1[(size_t)row * DMODEL + (col - DMODEL)] = (ushort)bf16rne(silu_f(v));
      }
    }
  }
}

// ---------------------------------------------------------------------------
// K2 fused_mid: conv+silu -> xc (LDS tile + global), delta GEMM (softplus,
// fp16 out), BC GEMM, scan pass1 -> hout/cumA. Block = (b, 64-l chunk).
// LDS: @0 xc bf16 [64 rows][32 chunks] swz c^(r&7)      (32 KB)
//      @32768 B dbuf 16KB x2 -> later delta fp16 [64][256] swz  (32 KB)
//      @65536 WBC bf16 [32][32c] swz -> later BC f32 [64][32]   (16 KB)
// delta tile swizzle: byte = row*512 + ((col*2) ^ (((row>>2)&3)<<5))
// ---------------------------------------------------------------------------
__global__ __launch_bounds__(256, 2) void fused_mid(
    const float* __restrict__ xin, const ushort* __restrict__ wdl,
    const ushort* __restrict__ wbc, const float* __restrict__ b_delta,
    const float* __restrict__ A_log, const float* __restrict__ conv_w,
    const float* __restrict__ conv_b, ushort* __restrict__ xc_g,
    ushort* __restrict__ dl_g, ushort* __restrict__ bc_g,
    float* __restrict__ hout, float* __restrict__ cumA) {
  __shared__ char smem[81920];
  const int tid = threadIdx.x, lane = tid & 63, wid = tid >> 6;
  const int b = blockIdx.x / NCHUNK, c = blockIdx.x % NCHUNK;
  const int l0 = c * LC;
  const size_t row0 = (size_t)b * LSEQ + l0;

  // ---- issue WBC staging (whole 32x256) early
  {
    const int rB = tid >> 5, cB = tid & 31;
    const ushort* gW = wbc + (size_t)rB * 256 + ((cB ^ (rB & 7)) * 8);
#pragma unroll
    for (int i = 0; i < 4; ++i)
      glds16(gW + (size_t)(8 * i) * 256, smem + 65536 + (8 * i + 2 * wid) * 512);
  }
  // ---- issue W_delta k-step 0
  const int rB4 = tid >> 2, cB4 = tid & 3;
  const int sB4 = (rB4 + (rB4 >> 2)) & 3;
  const ushort* gB = wdl + (size_t)rB4 * 256 + ((cB4 ^ sB4) * 8);
#pragma unroll
  for (int i = 0; i < 4; ++i)
    glds16(gB + (size_t)i * 64 * 256, smem + 32768 + i * 4096 + wid * 1024);

  // ---- conv + silu -> xc tile (LDS swizzled) + xc global
  {
    const int dq = tid & 31;
    const int d0 = dq * 8;
    float w0[8], w1[8], w2[8], cb[8];
#pragma unroll
    for (int k = 0; k < 8; ++k) {
      w0[k] = conv_w[(d0 + k) * 3 + 0];
      w1[k] = conv_w[(d0 + k) * 3 + 1];
      w2[k] = conv_w[(d0 + k) * 3 + 2];
      cb[k] = conv_b[d0 + k];
    }
#pragma unroll
    for (int it = 0; it < 8; ++it) {
      const int lr = it * 8 + (tid >> 5);
      const int l = l0 + lr;
      const size_t bp = (row0 + lr) * DMODEL + d0;
      float4 zf = {0.f, 0.f, 0.f, 0.f};
      float4 m0 = zf, m1 = zf, p0 = zf, p1 = zf;
      if (l > 0) {
        m0 = *(const float4*)(xin + bp - DMODEL);
        m1 = *(const float4*)(xin + bp - DMODEL + 4);
      }
      float4 c0 = *(const float4*)(xin + bp);
      float4 c1 = *(const float4*)(xin + bp + 4);
      if (l < LSEQ - 1) {
        p0 = *(const float4*)(xin + bp + DMODEL);
        p1 = *(const float4*)(xin + bp + DMODEL + 4);
      }
      float mv[8] = {m0.x, m0.y, m0.z, m0.w, m1.x, m1.y, m1.z, m1.w};
      float cv[8] = {c0.x, c0.y, c0.z, c0.w, c1.x, c1.y, c1.z, c1.w};
      float pv[8] = {p0.x, p0.y, p0.z, p0.w, p1.x, p1.y, p1.z, p1.w};
      float ov[8];
#pragma unroll
      for (int k = 0; k < 8; ++k) {
        float o = fmaf(w0[k], mv[k], fmaf(w1[k], cv[k], fmaf(w2[k], pv[k], cb[k])));
        ov[k] = silu_f(o);
      }
      uint4 r4;
      r4.x = pk2(ov[0], ov[1]);
      r4.y = pk2(ov[2], ov[3]);
      r4.z = pk2(ov[4], ov[5]);
      r4.w = pk2(ov[6], ov[7]);
      *(uint4*)(xc_g + bp) = r4;
      *(uint4*)(smem + lr * 512 + ((dq ^ (lr & 7)) * 16)) = r4;
    }
  }
  __syncthreads();  // xc tile + WBC + B-k0 ready

  // ---- delta GEMM: A = xc tile (full-A in LDS), B = W_delta streamed
  f32x4 acc[4][4];
#pragma unroll
  for (int i = 0; i < 4; ++i)
#pragma unroll
    for (int j = 0; j < 4; ++j) acc[i][j] = {0.f, 0.f, 0.f, 0.f};

  for (int step = 0; step < 8; ++step) {
    char* bufc = smem + 32768 + (step & 1) * 16384;
    if (step < 7) {
      char* bufn = smem + 32768 + ((step + 1) & 1) * 16384;
      const int k0 = (step + 1) * 32;
#pragma unroll
      for (int i = 0; i < 4; ++i)
        glds16(gB + (size_t)i * 64 * 256 + k0, bufn + i * 4096 + wid * 1024);
    }
    bf16x8 af[4], bfr[4];
#pragma unroll
    for (int i = 0; i < 4; ++i) {
      int r = i * 16 + (lane & 15);
      int sc = step * 4 + (lane >> 4);
      af[i] = *(const bf16x8*)(smem + r * 512 + ((sc ^ (r & 7)) * 16));
    }
#pragma unroll
    for (int j = 0; j < 4; ++j) {
      int r = wid * 64 + j * 16 + (lane & 15);
      int slot = (lane >> 4) ^ ((r + (r >> 2)) & 3);
      bfr[j] = *(const bf16x8*)(bufc + r * 64 + slot * 16);
    }
#pragma unroll
    for (int i = 0; i < 4; ++i)
#pragma unroll
      for (int j = 0; j < 4; ++j)
        acc[i][j] = __builtin_amdgcn_mfma_f32_16x16x32_bf16(af[i], bfr[j],
                                                            acc[i][j], 0, 0, 0);
    __syncthreads();
  }

  // ---- BC GEMM (pure LDS: xc tile x WBC), 16 rows/wave x 32 cols
  f32x4 accbc[2];
  accbc[0] = {0.f, 0.f, 0.f, 0.f};
  accbc[1] = {0.f, 0.f, 0.f, 0.f};
#pragma unroll
  for (int step = 0; step < 8; ++step) {
    int sc = step * 4 + (lane >> 4);
    int ra = wid * 16 + (lane & 15);
    bf16x8 a2 = *(const bf16x8*)(smem + ra * 512 + ((sc ^ (ra & 7)) * 16));
#pragma unroll
    for (int j = 0; j < 2; ++j) {
      int br = j * 16 + (lane & 15);
      bf16x8 b2 = *(const bf16x8*)(smem + 65536 + br * 512 + ((sc ^ (br & 7)) * 16));
      accbc[j] = __builtin_amdgcn_mfma_f32_16x16x32_bf16(a2, b2, accbc[j], 0, 0, 0);
    }
  }

  // ---- delta epilogue -> dtile fp16 [64][256] swizzled @32768
  const int rbase = (lane >> 4) * 4;
  const int cn = lane & 15;
#pragma unroll
  for (int i = 0; i < 4; ++i)
#pragma unroll
    for (int j = 0; j < 4; ++j) {
      int col = wid * 64 + j * 16 + cn;
      float bs = b_delta[col];
#pragma unroll
      for (int r = 0; r < 4; ++r) {
        int row = i * 16 + rbase + r;
        *(ushort*)(smem + 32768 + row * 512 +
                   ((col * 2) ^ (((row >> 2) & 3) << 5))) =
            f2h(softplus_f(acc[i][j][r] + bs));
      }
    }
  __syncthreads();  // WBC reads + dtile writes done

  // ---- BC epilogue: BC f32 tile @65536 (over WBC) + bc_g global (bf16)
#pragma unroll
  for (int j = 0; j < 2; ++j)
#pragma unroll
    for (int r = 0; r < 4; ++r) {
      int row = wid * 16 + rbase + r;
      int col = j * 16 + cn;
      ushort bv = (ushort)bf16rne(accbc[j][r]);
      ((float*)(smem + 65536))[row * 32 + col] = bf2f(bv);
      bc_g[(row0 + row) * 32 + col] = bv;
    }
  // ---- dl_g coalesced write from dtile (chunk XOR'd per swizzle)
#pragma unroll
  for (int it = 0; it < 8; ++it) {
    int idx = it * 256 + tid;
    int row = idx >> 5, ch = idx & 31;
    *(uint4*)(dl_g + (row0 + row) * DMODEL + ch * 8) =
        *(const uint4*)(smem + 32768 + row * 512 +
                        ((ch ^ (((row >> 2) & 3) << 1)) * 16));
  }
  __syncthreads();  // BC f32 visible

  // ---- scan pass1 (all inputs in LDS)
  float Aa2[NST];
#pragma unroll
  for (int q = 0; q < 4; ++q) {
    float4 v = *(const float4*)(A_log + tid * NST + q * 4);
    Aa2[q * 4 + 0] = -LOG2E * __expf(v.x);
    Aa2[q * 4 + 1] = -LOG2E * __expf(v.y);
    Aa2[q * 4 + 2] = -LOG2E * __expf(v.z);
    Aa2[q * 4 + 3] = -LOG2E * __expf(v.w);
  }
  bool pm = true;
#pragma unroll
  for (int n = 1; n < NST; ++n)
    pm = pm && (fabsf(Aa2[n] - (float)(n + 1) * Aa2[0]) <=
                1e-3f * fabsf(Aa2[n]));
  float h[NST];
#pragma unroll
  for (int n = 0; n < NST; ++n) h[n] = 0.f;
  float sdt = 0.f;
  const int uoff0 = (tid & 7) * 2;
  const int uchunk = tid >> 3;
  if (pm) {
#pragma unroll 4
    for (int l = 0; l < LC; ++l) {
      float dt = h2f(*(const ushort*)(smem + 32768 + l * 512 +
                                      ((tid * 2) ^ (((l >> 2) & 3) << 5))));
      float u = bf2f(*(const ushort*)(smem + l * 512 +
                                      ((uchunk ^ (l & 7)) * 16) + uoff0));
      sdt += dt;
      float dtu = dt * u;
      const float* Bp = (const float*)(smem + 65536) + l * 32;
      f32x4 B0 = *(const f32x4*)(Bp);
      f32x4 B1 = *(const f32x4*)(Bp + 4);
      f32x4 B2 = *(const f32x4*)(Bp + 8);
      f32x4 B3 = *(const f32x4*)(Bp + 12);
      float Bv[NST] = {B0.x, B0.y, B0.z, B0.w, B1.x, B1.y, B1.z, B1.w,
                       B2.x, B2.y, B2.z, B2.w, B3.x, B3.y, B3.z, B3.w};
      float p[NST];
      pow16(__builtin_amdgcn_exp2f(dt * Aa2[0]), p);
#pragma unroll
      for (int n = 0; n < NST; ++n) h[n] = fmaf(p[n], h[n], dtu * Bv[n]);
    }
  } else {
#pragma unroll 4
    for (int l = 0; l < LC; ++l) {
      float dt = h2f(*(const ushort*)(smem + 32768 + l * 512 +
                                      ((tid * 2) ^ (((l >> 2) & 3) << 5))));
      float u = bf2f(*(const ushort*)(smem + l * 512 +
                                      ((uchunk ^ (l & 7)) * 16) + uoff0));
      sdt += dt;
      float dtu = dt * u;
      const float* Bp = (const float*)(smem + 65536) + l * 32;
      f32x4 B0 = *(const f32x4*)(Bp);
      f32x4 B1 = *(const f32x4*)(Bp + 4);
      f32x4 B2 = *(const f32x4*)(Bp + 8);
      f32x4 B3 = *(const f32x4*)(Bp + 12);
      float Bv[NST] = {B0.x, B0.y, B0.z, B0.w, B1.x, B1.y, B1.z, B1.w,
                       B2.x, B2.y, B2.z, B2.w, B3.x, B3.y, B3.z, B3.w};
#pragma unroll
      for (int n = 0; n < NST; ++n) {
        float ab = __builtin_amdgcn_exp2f(dt * Aa2[n]);
        h[n] = fmaf(ab, h[n], dtu * Bv[n]);
      }
    }
  }
  float cum[NST];
  if (pm) {
    pow16(__builtin_amdgcn_exp2f(sdt * Aa2[0]), cum);
  } else {
#pragma unroll
    for (int n = 0; n < NST; ++n)
      cum[n] = __builtin_amdgcn_exp2f(sdt * Aa2[n]);
  }
  const size_t ob = (((size_t)(b * NCHUNK + c)) * DMODEL + tid) * NST;
#pragma unroll
  for (int q = 0; q < 4; ++q) {
    float4 hv = {h[q * 4 + 0], h[q * 4 + 1], h[q * 4 + 2], h[q * 4 + 3]};
    *(float4*)(hout + ob + q * 4) = hv;
    float4 cvv = {cum[q * 4 + 0], cum[q * 4 + 1], cum[q * 4 + 2],
                  cum[q * 4 + 3]};
    *(float4*)(cumA + ob + q * 4) = cvv;
  }
}

// ---------------------------------------------------------------------------
// Scan combine: sequential over chunks; in-place h_out -> h_in (fp32).
// ---------------------------------------------------------------------------
__global__ __launch_bounds__(256) void scan_combine(
    float* __restrict__ hstate, const float* __restrict__ cumA) {
  const int t = blockIdx.x * 256 + threadIdx.x;
  const int n = t & (NST - 1);
  const int dd = (t / NST) & (DMODEL - 1);
  const int b = t / (NST * DMODEL);
  float h = 0.f;
  for (int c = 0; c < NCHUNK; ++c) {
    size_t idx = (((size_t)(b * NCHUNK + c)) * DMODEL + dd) * NST + n;
    float ho = hstate[idx];
    float ca = cumA[idx];
    hstate[idx] = h;
    h = fmaf(ca, h, ho);
  }
}

// ---------------------------------------------------------------------------
// K3 fused_out: scan pass3 -> y_pre LDS tile -> GEMM with W_out -> d_out.
// LDS: @0 ypre bf16 [64][32c] swz c^(r&7) (32 KB); @32768 B dbuf 16KBx2;
//      @65536 BC f32 [64][32] (8 KB).
// ---------------------------------------------------------------------------
__global__ __launch_bounds__(256, 2) void fused_out(
    const ushort* __restrict__ dl, const ushort* __restrict__ xcb,
    const ushort* __restrict__ szy, const ushort* __restrict__ bcb,
    const float* __restrict__ A_log, const float* __restrict__ hin,
    const float* __restrict__ Dskip, const ushort* __restrict__ wout,
    const float* __restrict__ b_out, float* __restrict__ out) {
  __shared__ char smem[73728];
  const int tid = threadIdx.x, lane = tid & 63, wid = tid >> 6;
  const int b = blockIdx.x / NCHUNK, c = blockIdx.x % NCHUNK;
  const int l0 = c * LC;
  const size_t row0 = (size_t)b * LSEQ + l0;

  // stage BC f32 tile
#pragma unroll
  for (int i = 0; i < 2; ++i) {
    int t = tid + i * 256;
    int r = t >> 3, q = t & 7;
    uint2 v = *(const uint2*)(bcb + (row0 + r) * 32 + q * 4);
    float* dp = (float*)(smem + 65536) + r * 32 + q * 4;
    dp[0] = bf2f((ushort)(v.x & 0xffff));
    dp[1] = bf2f((ushort)(v.x >> 16));
    dp[2] = bf2f((ushort)(v.y & 0xffff));
    dp[3] = bf2f((ushort)(v.y >> 16));
  }
  // issue W_out k-step 0
  const int rB4 = tid >> 2, cB4 = tid & 3;
  const int sB4 = (rB4 + (rB4 >> 2)) & 3;
  const ushort* gB = wout + (size_t)rB4 * 256 + ((cB4 ^ sB4) * 8);
#pragma unroll
  for (int i = 0; i < 4; ++i)
    glds16(gB + (size_t)i * 64 * 256, smem + 32768 + i * 4096 + wid * 1024);

  float Aa2[NST];
#pragma unroll
  for (int q = 0; q < 4; ++q) {
    float4 v = *(const float4*)(A_log + tid * NST + q * 4);
    Aa2[q * 4 + 0] = -LOG2E * __expf(v.x);
    Aa2[q * 4 + 1] = -LOG2E * __expf(v.y);
    Aa2[q * 4 + 2] = -LOG2E * __expf(v.z);
    Aa2[q * 4 + 3] = -LOG2E * __expf(v.w);
  }
  bool pm = true;
#pragma unroll
  for (int n = 1; n < NST; ++n)
    pm = pm && (fabsf(Aa2[n] - (float)(n + 1) * Aa2[0]) <=
                1e-3f * fabsf(Aa2[n]));
  float h[NST];
  const size_t hb = (((size_t)(b * NCHUNK + c)) * DMODEL + tid) * NST;
#pragma unroll
  for (int q = 0; q < 4; ++q) {
    float4 v = *(const float4*)(hin + hb + q * 4);
    h[q * 4 + 0] = v.x;
    h[q * 4 + 1] = v.y;
    h[q * 4 + 2] = v.z;
    h[q * 4 + 3] = v.w;
  }
  const float dsk = Dskip[tid];
  __syncthreads();  // BC tile ready

  // ---- scan (global scalar reads w/ rolling prefetch), y_pre -> LDS
  const size_t base = row0 * DMODEL + tid;
  const int ywoff = (tid & 7) * 2;
  const int ywchunk = tid >> 3;
  ushort dtr[4], ur[4], zr[4];
#pragma unroll
  for (int j = 0; j < 4; ++j) {
    dtr[j] = dl[base + (size_t)j * DMODEL];
    ur[j] = xcb[base + (size_t)j * DMODEL];
    zr[j] = szy[base + (size_t)j * DMODEL];
  }
  for (int lb = 0; lb < LC / 4; ++lb) {
    ushort dtn[4], un[4], zn[4];
    if (lb < LC / 4 - 1) {
      size_t nb = base + (size_t)(lb * 4 + 4) * DMODEL;
#pragma unroll
      for (int j = 0; j < 4; ++j) {
        dtn[j] = dl[nb + (size_t)j * DMODEL];
        un[j] = xcb[nb + (size_t)j * DMODEL];
        zn[j] = szy[nb + (size_t)j * DMODEL];
      }
    }
#pragma unroll
    for (int j = 0; j < 4; ++j) {
      int l = lb * 4 + j;
      float dt = h2f(dtr[j]);
      float u = bf2f(ur[j]);
      float dtu = dt * u;
      const float* Bp = (const float*)(smem + 65536) + l * 32;
      f32x4 B0 = *(const f32x4*)(Bp);
      f32x4 B1 = *(const f32x4*)(Bp + 4);
      f32x4 B2 = *(const f32x4*)(Bp + 8);
      f32x4 B3 = *(const f32x4*)(Bp + 12);
      f32x4 C0 = *(const f32x4*)(Bp + 16);
      f32x4 C1 = *(const f32x4*)(Bp + 20);
      f32x4 C2 = *(const f32x4*)(Bp + 24);
      f32x4 C3 = *(const f32x4*)(Bp + 28);
      float Bv[NST] = {B0.x, B0.y, B0.z, B0.w, B1.x, B1.y, B1.z, B1.w,
                       B2.x, B2.y, B2.z, B2.w, B3.x, B3.y, B3.z, B3.w};
      float Cv[NST] = {C0.x, C0.y, C0.z, C0.w, C1.x, C1.y, C1.z, C1.w,
                       C2.x, C2.y, C2.z, C2.w, C3.x, C3.y, C3.z, C3.w};
      float y = 0.f;
      if (pm) {
        float p[NST];
        pow16(__builtin_amdgcn_exp2f(dt * Aa2[0]), p);
#pragma unroll
        for (int n = 0; n < NST; ++n) {
          h[n] = fmaf(p[n], h[n], dtu * Bv[n]);
          y = fmaf(h[n], Cv[n], y);
        }
      } else {
#pragma unroll
        for (int n = 0; n < NST; ++n) {
          float ab = __builtin_amdgcn_exp2f(dt * Aa2[n]);
          h[n] = fmaf(ab, h[n], dtu * Bv[n]);
          y = fmaf(h[n], Cv[n], y);
        }
      }
      float yp = (y + u * dsk) * bf2f(zr[j]);
      *(ushort*)(smem + l * 512 + ((ywchunk ^ (l & 7)) * 16) + ywoff) =
          (ushort)bf16rne(yp);
    }
#pragma unroll
    for (int j = 0; j < 4; ++j) {
      dtr[j] = dtn[j];
      ur[j] = un[j];
      zr[j] = zn[j];
    }
  }
  __syncthreads();  // ypre tile complete

  // ---- output GEMM: A = ypre tile, B = W_out streamed
  f32x4 acc[4][4];
#pragma unroll
  for (int i = 0; i < 4; ++i)
#pragma unroll
    for (int j = 0; j < 4; ++j) acc[i][j] = {0.f, 0.f, 0.f, 0.f};

  for (int step = 0; step < 8; ++step) {
    char* bufc = smem + 32768 + (step & 1) * 16384;
    if (step < 7) {
      char* bufn = smem + 32768 + ((step + 1) & 1) * 16384;
      const int k0 = (step + 1) * 32;
#pragma unroll
      for (int i = 0; i < 4; ++i)
        glds16(gB + (size_t)i * 64 * 256 + k0, bufn + i * 4096 + wid * 1024);
    }
    bf16x8 af[4], bfr[4];
#pragma unroll
    for (int i = 0; i < 4; ++i) {
      int r = i * 16 + (lane & 15);
      int sc = step * 4 + (lane >> 4);
      af[i] = *(const bf16x8*)(smem + r * 512 + ((sc ^ (r & 7)) * 16));
    }
#pragma unroll
    for (int j = 0; j < 4; ++j) {
      int r = wid * 64 + j * 16 + (lane & 15);
      int slot = (lane >> 4) ^ ((r + (r >> 2)) & 3);
      bfr[j] = *(const bf16x8*)(bufc + r * 64 + slot * 16);
    }
#pragma unroll
    for (int i = 0; i < 4; ++i)
#pragma unroll
      for (int j = 0; j < 4; ++j)
        acc[i][j] = __builtin_amdgcn_mfma_f32_16x16x32_bf16(af[i], bfr[j],
                                                            acc[i][j], 0, 0, 0);
    __syncthreads();
  }

  const int rbase = (lane >> 4) * 4;
  const int cn = lane & 15;
#pragma unroll
  for (int i = 0; i < 4; ++i)
#pragma unroll
    for (int j = 0; j < 4; ++j) {
      int col = wid * 64 + j * 16 + cn;
      float bs = b_out[col];
#pragma unroll
      for (int r = 0; r < 4; ++r) {
        int row = i * 16 + rbase + r;
        out[(row0 + row) * DMODEL + col] = acc[i][j][r] + bs;
      }
    }
}

// ---------------------------------------------------------------------------
extern "C" void kernel_launch(void* const* d_in, const int* in_sizes, int n_in,
                              void* d_out, int out_size, void* d_ws,
                              size_t ws_size, hipStream_t stream) {
  const float* x       = (const float*)d_in[0];
  const float* A_log   = (const float*)d_in[1];
  const float* D_skip  = (const float*)d_in[2];
  const float* W_B     = (const float*)d_in[3];
  const float* W_C     = (const float*)d_in[4];
  const float* W_delta = (const float*)d_in[5];
  const float* b_delta = (const float*)d_in[6];
  const float* W_in    = (const float*)d_in[7];
  const float* b_in    = (const float*)d_in[8];
  const float* W_out   = (const float*)d_in[9];
  const float* b_out   = (const float*)d_in[10];
  const float* conv_w  = (const float*)d_in[11];
  const float* conv_b  = (const float*)d_in[12];

  const size_t MD = (size_t)MROWS * DMODEL;                 // 16.78M
  const size_t HP = (size_t)BATCH * NCHUNK * DMODEL * NST;  // 4.19M
  float* xin   = (float*)d_ws;              // x_in fp32 [MD]
  ushort* dl   = (ushort*)(xin + MD);       // delta fp16 [MD]
  ushort* szy  = dl + MD;                   // silu(z) bf16 [MD]
  ushort* xcb  = szy + MD;                  // xc bf16 [MD]
  ushort* bcb  = xcb + MD;                  // bc bf16 [MROWS*32]
  float* hst   = (float*)(bcb + (size_t)MROWS * 32);  // h_out -> h_in [HP]
  float* cumA  = hst + HP;                  // [HP]
  ushort* wbf  = (ushort*)(cumA + HP);      // bf16 weights, 270336

  cvt_weights<<<dim3(132), 256, 0, stream>>>(W_in, W_delta, W_out, W_B, W_C, wbf);
  gemm_in<<<dim3(2, MROWS / 64), 256, 0, stream>>>(x, wbf, b_in, xin, szy);
  fused_mid<<<dim3(BATCH * NCHUNK), 256, 0, stream>>>(
      xin, wbf + 131072, wbf + 262144, b_delta, A_log, conv_w, conv_b,
      xcb, dl, bcb, hst, cumA);
  scan_combine<<<dim3(BATCH * DMODEL * NST / 256), 256, 0, stream>>>(hst, cumA);
  fused_out<<<dim3(BATCH * NCHUNK), 256, 0, stream>>>(
      dl, xcb, szy, bcb, A_log, hst, D_skip, wbf + 196608, b_out,
      (float*)d_out);
}

// Round 8
// 244.619 us; speedup vs baseline: 1.3125x; 1.0031x over previous
//
#include <hip/hip_runtime.h>
#include <hip/hip_bf16.h>
#include <math.h>

#define BATCH 16
#define LSEQ 4096
#define DMODEL 256
#define NST 16
#define LC 64
#define NCHUNK (LSEQ / LC)    // 64
#define MROWS (BATCH * LSEQ)  // 65536
#define LOG2E 1.44269504088896340736f

typedef float f32x4 __attribute__((ext_vector_type(4)));
typedef short bf16x8 __attribute__((ext_vector_type(8)));

__device__ __forceinline__ float silu_f(float v) { return v / (1.f + __expf(-v)); }
__device__ __forceinline__ float softplus_f(float v) {
  return fmaxf(v, 0.f) + log1pf(__expf(-fabsf(v)));
}
__device__ __forceinline__ uint bf16rne(float f) {
  uint u = __float_as_uint(f);
  return (u + 0x7fffu + ((u >> 16) & 1u)) >> 16;
}
__device__ __forceinline__ float bf2f(ushort u) {
  return __uint_as_float((uint)u << 16);
}
__device__ __forceinline__ ushort f2h(float v) {
  _Float16 h = (_Float16)v;
  return __builtin_bit_cast(ushort, h);
}
__device__ __forceinline__ float h2f(ushort u) {
  return (float)__builtin_bit_cast(_Float16, u);
}
__device__ __forceinline__ uint pk2(float x, float y) {
  return bf16rne(x) | (bf16rne(y) << 16);
}
__device__ __forceinline__ uint4 pk8(float4 a, float4 b) {
  uint4 r;
  r.x = pk2(a.x, a.y);
  r.y = pk2(a.z, a.w);
  r.z = pk2(b.x, b.y);
  r.w = pk2(b.z, b.w);
  return r;
}

// p[n] = e1^(n+1), 15 muls, dep depth 4
__device__ __forceinline__ void pow16(float e1, float* p) {
  p[0] = e1;
  p[1] = e1 * e1;
  p[2] = p[1] * e1;
  p[3] = p[1] * p[1];
  p[4] = p[3] * e1;
  p[5] = p[3] * p[1];
  p[6] = p[3] * p[2];
  p[7] = p[3] * p[3];
  p[8] = p[7] * e1;
  p[9] = p[7] * p[1];
  p[10] = p[7] * p[2];
  p[11] = p[7] * p[3];
  p[12] = p[7] * p[4];
  p[13] = p[7] * p[5];
  p[14] = p[7] * p[6];
  p[15] = p[7] * p[7];
}

// async global(bf16)->LDS, 16 B per lane (dest = wave-uniform base + lane*16)
__device__ __forceinline__ void glds16(const ushort* g, char* l) {
  __builtin_amdgcn_global_load_lds(
      (const __attribute__((address_space(1))) void*)g,
      (__attribute__((address_space(3))) void*)l, 16, 0, 0);
}

// ---------------------------------------------------------------------------
// Weight fp32->bf16 convert. dst layout (ushort offsets):
//   [0,131072) W_in | [131072,196608) W_delta | [196608,262144) W_out
//   [262144,266240) W_B | [266240,270336) W_C
// ---------------------------------------------------------------------------
__global__ __launch_bounds__(256) void cvt_weights(
    const float* __restrict__ Win, const float* __restrict__ Wd,
    const float* __restrict__ Wo, const float* __restrict__ WB,
    const float* __restrict__ WC, ushort* __restrict__ dst) {
  size_t i = ((size_t)blockIdx.x * 256 + threadIdx.x) * 8;
  if (i >= 270336) return;
  const float* s;
  size_t o;
  if (i < 131072)      { s = Win; o = i; }
  else if (i < 196608) { s = Wd;  o = i - 131072; }
  else if (i < 262144) { s = Wo;  o = i - 196608; }
  else if (i < 266240) { s = WB;  o = i - 262144; }
  else                 { s = WC;  o = i - 266240; }
  float4 a = *(const float4*)(s + o);
  float4 b = *(const float4*)(s + o + 4);
  *(uint4*)(dst + i) = pk8(a, b);
}

// ---------------------------------------------------------------------------
// MODE0 GEMM: xz = x @ W_in^T + b_in. Tile 64x256, grid (2, M/64);
// col<256 -> x_in fp32, col>=256 -> silu(z) bf16.
// ---------------------------------------------------------------------------
__global__ __launch_bounds__(256, 4) void gemm_in(
    const float* __restrict__ A, const ushort* __restrict__ Bbf,
    const float* __restrict__ bias, float* __restrict__ out0,
    ushort* __restrict__ out1) {
  constexpr int KD = 256;
  __shared__ char smem[40960];  // buf stride 20480: A 4KB @0, B 16KB @4096
  const int tid = threadIdx.x;
  const int lane = tid & 63, wid = tid >> 6;
  const int M0 = blockIdx.y * 64;
  const int N0 = blockIdx.x * 256;

  const int rA = tid >> 2, cA = tid & 3;
  const int sA = (rA + (rA >> 2)) & 3;
  const int ldsAoff = rA * 64 + ((cA ^ sA) * 16);
  const float* gA32 = A + (size_t)(M0 + rA) * KD + cA * 8;
  const ushort* gB = Bbf + (size_t)(N0 + rA) * KD + ((cA ^ sA) * 8);

  f32x4 acc[4][4];
#pragma unroll
  for (int i = 0; i < 4; ++i)
#pragma unroll
    for (int j = 0; j < 4; ++j) acc[i][j] = {0.f, 0.f, 0.f, 0.f};

  {
#pragma unroll
    for (int i = 0; i < 4; ++i)
      glds16(gB + (size_t)i * 64 * KD, smem + 4096 + i * 4096 + wid * 1024);
    float4 a0 = *(const float4*)(gA32);
    float4 a1 = *(const float4*)(gA32 + 4);
    *(uint4*)(smem + ldsAoff) = pk8(a0, a1);
  }
  __syncthreads();

  for (int step = 0; step < 8; ++step) {
    const int cur = step & 1;
    char* bufc = smem + cur * 20480;
    char* bufn = smem + (cur ^ 1) * 20480;
    float4 na0, na1;
    if (step < 7) {
      const int k0 = (step + 1) * 32;
#pragma unroll
      for (int i = 0; i < 4; ++i)
        glds16(gB + (size_t)i * 64 * KD + k0,
               bufn + 4096 + i * 4096 + wid * 1024);
      na0 = *(const float4*)(gA32 + k0);
      na1 = *(const float4*)(gA32 + k0 + 4);
    }
    bf16x8 af[4], bfr[4];
#pragma unroll
    for (int i = 0; i < 4; ++i) {
      int r = i * 16 + (lane & 15);
      int slot = (lane >> 4) ^ ((r + (r >> 2)) & 3);
      af[i] = *(const bf16x8*)(bufc + r * 64 + slot * 16);
    }
#pragma unroll
    for (int j = 0; j < 4; ++j) {
      int r = wid * 64 + j * 16 + (lane & 15);
      int slot = (lane >> 4) ^ ((r + (r >> 2)) & 3);
      bfr[j] = *(const bf16x8*)(bufc + 4096 + r * 64 + slot * 16);
    }
#pragma unroll
    for (int i = 0; i < 4; ++i)
#pragma unroll
      for (int j = 0; j < 4; ++j)
        acc[i][j] = __builtin_amdgcn_mfma_f32_16x16x32_bf16(af[i], bfr[j],
                                                            acc[i][j], 0, 0, 0);
    if (step < 7) *(uint4*)(bufn + ldsAoff) = pk8(na0, na1);
    __syncthreads();
  }

  const int rbase = (lane >> 4) * 4;
  const int cn = lane & 15;
#pragma unroll
  for (int i = 0; i < 4; ++i) {
#pragma unroll
    for (int j = 0; j < 4; ++j) {
      int col = N0 + wid * 64 + j * 16 + cn;
      float bs = bias[col];
#pragma unroll
      for (int r = 0; r < 4; ++r) {
        int row = M0 + i * 16 + rbase + r;
        float v = acc[i][j][r] + bs;
        if (col < DMODEL)
          out0[(size_t)row * DMODEL + col] = v;
        else
          out1[(size_t)row * DMODEL + (col - DMODEL)] = (ushort)bf16rne(silu_f(v));
      }
    }
  }
}

// ---------------------------------------------------------------------------
// K2 fused_mid: conv+silu -> xc (LDS tile + global), delta GEMM (softplus,
// fp16 out), BC GEMM, scan pass1 -> hout/cumA. Block = (b, 64-l chunk).
// LDS: @0 xc bf16 [64 rows][32 chunks] swz c^(r&7)      (32 KB)
//      @32768 B dbuf 16KB x2 -> later delta fp16 [64][256] swz  (32 KB)
//      @65536 WBC bf16 [32][32c] swz -> later BC f32 [64][32]   (16 KB)
// delta tile swizzle: byte = row*512 + ((col*2) ^ (((row>>2)&3)<<5))
// ---------------------------------------------------------------------------
__global__ __launch_bounds__(256, 2) void fused_mid(
    const float* __restrict__ xin, const ushort* __restrict__ wdl,
    const ushort* __restrict__ wbc, const float* __restrict__ b_delta,
    const float* __restrict__ A_log, const float* __restrict__ conv_w,
    const float* __restrict__ conv_b, ushort* __restrict__ xc_g,
    ushort* __restrict__ dl_g, ushort* __restrict__ bc_g,
    float* __restrict__ hout, float* __restrict__ cumA) {
  __shared__ char smem[81920];
  const int tid = threadIdx.x, lane = tid & 63, wid = tid >> 6;
  const int b = blockIdx.x / NCHUNK, c = blockIdx.x % NCHUNK;
  const int l0 = c * LC;
  const size_t row0 = (size_t)b * LSEQ + l0;

  // ---- issue WBC staging (whole 32x256) early
  {
    const int rB = tid >> 5, cB = tid & 31;
    const ushort* gW = wbc + (size_t)rB * 256 + ((cB ^ (rB & 7)) * 8);
#pragma unroll
    for (int i = 0; i < 4; ++i)
      glds16(gW + (size_t)(8 * i) * 256, smem + 65536 + (8 * i + 2 * wid) * 512);
  }
  // ---- issue W_delta k-step 0
  const int rB4 = tid >> 2, cB4 = tid & 3;
  const int sB4 = (rB4 + (rB4 >> 2)) & 3;
  const ushort* gB = wdl + (size_t)rB4 * 256 + ((cB4 ^ sB4) * 8);
#pragma unroll
  for (int i = 0; i < 4; ++i)
    glds16(gB + (size_t)i * 64 * 256, smem + 32768 + i * 4096 + wid * 1024);

  // ---- conv + silu -> xc tile (LDS swizzled) + xc global
  {
    const int dq = tid & 31;
    const int d0 = dq * 8;
    float w0[8], w1[8], w2[8], cb[8];
#pragma unroll
    for (int k = 0; k < 8; ++k) {
      w0[k] = conv_w[(d0 + k) * 3 + 0];
      w1[k] = conv_w[(d0 + k) * 3 + 1];
      w2[k] = conv_w[(d0 + k) * 3 + 2];
      cb[k] = conv_b[d0 + k];
    }
#pragma unroll
    for (int it = 0; it < 8; ++it) {
      const int lr = it * 8 + (tid >> 5);
      const int l = l0 + lr;
      const size_t bp = (row0 + lr) * DMODEL + d0;
      float4 zf = {0.f, 0.f, 0.f, 0.f};
      float4 m0 = zf, m1 = zf, p0 = zf, p1 = zf;
      if (l > 0) {
        m0 = *(const float4*)(xin + bp - DMODEL);
        m1 = *(const float4*)(xin + bp - DMODEL + 4);
      }
      float4 c0 = *(const float4*)(xin + bp);
      float4 c1 = *(const float4*)(xin + bp + 4);
      if (l < LSEQ - 1) {
        p0 = *(const float4*)(xin + bp + DMODEL);
        p1 = *(const float4*)(xin + bp + DMODEL + 4);
      }
      float mv[8] = {m0.x, m0.y, m0.z, m0.w, m1.x, m1.y, m1.z, m1.w};
      float cv[8] = {c0.x, c0.y, c0.z, c0.w, c1.x, c1.y, c1.z, c1.w};
      float pv[8] = {p0.x, p0.y, p0.z, p0.w, p1.x, p1.y, p1.z, p1.w};
      float ov[8];
#pragma unroll
      for (int k = 0; k < 8; ++k) {
        float o = fmaf(w0[k], mv[k], fmaf(w1[k], cv[k], fmaf(w2[k], pv[k], cb[k])));
        ov[k] = silu_f(o);
      }
      uint4 r4;
      r4.x = pk2(ov[0], ov[1]);
      r4.y = pk2(ov[2], ov[3]);
      r4.z = pk2(ov[4], ov[5]);
      r4.w = pk2(ov[6], ov[7]);
      *(uint4*)(xc_g + bp) = r4;
      *(uint4*)(smem + lr * 512 + ((dq ^ (lr & 7)) * 16)) = r4;
    }
  }
  __syncthreads();  // xc tile + WBC + B-k0 ready

  // ---- delta GEMM: A = xc tile (full-A in LDS), B = W_delta streamed
  f32x4 acc[4][4];
#pragma unroll
  for (int i = 0; i < 4; ++i)
#pragma unroll
    for (int j = 0; j < 4; ++j) acc[i][j] = {0.f, 0.f, 0.f, 0.f};

  for (int step = 0; step < 8; ++step) {
    char* bufc = smem + 32768 + (step & 1) * 16384;
    if (step < 7) {
      char* bufn = smem + 32768 + ((step + 1) & 1) * 16384;
      const int k0 = (step + 1) * 32;
#pragma unroll
      for (int i = 0; i < 4; ++i)
        glds16(gB + (size_t)i * 64 * 256 + k0, bufn + i * 4096 + wid * 1024);
    }
    bf16x8 af[4], bfr[4];
#pragma unroll
    for (int i = 0; i < 4; ++i) {
      int r = i * 16 + (lane & 15);
      int sc = step * 4 + (lane >> 4);
      af[i] = *(const bf16x8*)(smem + r * 512 + ((sc ^ (r & 7)) * 16));
    }
#pragma unroll
    for (int j = 0; j < 4; ++j) {
      int r = wid * 64 + j * 16 + (lane & 15);
      int slot = (lane >> 4) ^ ((r + (r >> 2)) & 3);
      bfr[j] = *(const bf16x8*)(bufc + r * 64 + slot * 16);
    }
#pragma unroll
    for (int i = 0; i < 4; ++i)
#pragma unroll
      for (int j = 0; j < 4; ++j)
        acc[i][j] = __builtin_amdgcn_mfma_f32_16x16x32_bf16(af[i], bfr[j],
                                                            acc[i][j], 0, 0, 0);
    __syncthreads();
  }

  // ---- BC GEMM (pure LDS: xc tile x WBC), 16 rows/wave x 32 cols
  f32x4 accbc[2];
  accbc[0] = {0.f, 0.f, 0.f, 0.f};
  accbc[1] = {0.f, 0.f, 0.f, 0.f};
#pragma unroll
  for (int step = 0; step < 8; ++step) {
    int sc = step * 4 + (lane >> 4);
    int ra = wid * 16 + (lane & 15);
    bf16x8 a2 = *(const bf16x8*)(smem + ra * 512 + ((sc ^ (ra & 7)) * 16));
#pragma unroll
    for (int j = 0; j < 2; ++j) {
      int br = j * 16 + (lane & 15);
      bf16x8 b2 = *(const bf16x8*)(smem + 65536 + br * 512 + ((sc ^ (br & 7)) * 16));
      accbc[j] = __builtin_amdgcn_mfma_f32_16x16x32_bf16(a2, b2, accbc[j], 0, 0, 0);
    }
  }

  // ---- delta epilogue -> dtile fp16 [64][256] swizzled @32768
  const int rbase = (lane >> 4) * 4;
  const int cn = lane & 15;
#pragma unroll
  for (int i = 0; i < 4; ++i)
#pragma unroll
    for (int j = 0; j < 4; ++j) {
      int col = wid * 64 + j * 16 + cn;
      float bs = b_delta[col];
#pragma unroll
      for (int r = 0; r < 4; ++r) {
        int row = i * 16 + rbase + r;
        *(ushort*)(smem + 32768 + row * 512 +
                   ((col * 2) ^ (((row >> 2) & 3) << 5))) =
            f2h(softplus_f(acc[i][j][r] + bs));
      }
    }
  __syncthreads();  // WBC reads + dtile writes done

  // ---- BC epilogue: BC f32 tile @65536 (over WBC) + bc_g global (bf16)
#pragma unroll
  for (int j = 0; j < 2; ++j)
#pragma unroll
    for (int r = 0; r < 4; ++r) {
      int row = wid * 16 + rbase + r;
      int col = j * 16 + cn;
      ushort bv = (ushort)bf16rne(accbc[j][r]);
      ((float*)(smem + 65536))[row * 32 + col] = bf2f(bv);
      bc_g[(row0 + row) * 32 + col] = bv;
    }
  // ---- dl_g coalesced write from dtile (chunk XOR'd per swizzle)
#pragma unroll
  for (int it = 0; it < 8; ++it) {
    int idx = it * 256 + tid;
    int row = idx >> 5, ch = idx & 31;
    *(uint4*)(dl_g + (row0 + row) * DMODEL + ch * 8) =
        *(const uint4*)(smem + 32768 + row * 512 +
                        ((ch ^ (((row >> 2) & 3) << 1)) * 16));
  }
  __syncthreads();  // BC f32 visible

  // ---- scan pass1 (all inputs in LDS)
  float Aa2[NST];
#pragma unroll
  for (int q = 0; q < 4; ++q) {
    float4 v = *(const float4*)(A_log + tid * NST + q * 4);
    Aa2[q * 4 + 0] = -LOG2E * __expf(v.x);
    Aa2[q * 4 + 1] = -LOG2E * __expf(v.y);
    Aa2[q * 4 + 2] = -LOG2E * __expf(v.z);
    Aa2[q * 4 + 3] = -LOG2E * __expf(v.w);
  }
  bool pm = true;
#pragma unroll
  for (int n = 1; n < NST; ++n)
    pm = pm && (fabsf(Aa2[n] - (float)(n + 1) * Aa2[0]) <=
                1e-3f * fabsf(Aa2[n]));
  float h[NST];
#pragma unroll
  for (int n = 0; n < NST; ++n) h[n] = 0.f;
  float sdt = 0.f;
  const int uoff0 = (tid & 7) * 2;
  const int uchunk = tid >> 3;
  if (pm) {
#pragma unroll 4
    for (int l = 0; l < LC; ++l) {
      float dt = h2f(*(const ushort*)(smem + 32768 + l * 512 +
                                      ((tid * 2) ^ (((l >> 2) & 3) << 5))));
      float u = bf2f(*(const ushort*)(smem + l * 512 +
                                      ((uchunk ^ (l & 7)) * 16) + uoff0));
      sdt += dt;
      float dtu = dt * u;
      const float* Bp = (const float*)(smem + 65536) + l * 32;
      f32x4 B0 = *(const f32x4*)(Bp);
      f32x4 B1 = *(const f32x4*)(Bp + 4);
      f32x4 B2 = *(const f32x4*)(Bp + 8);
      f32x4 B3 = *(const f32x4*)(Bp + 12);
      float Bv[NST] = {B0.x, B0.y, B0.z, B0.w, B1.x, B1.y, B1.z, B1.w,
                       B2.x, B2.y, B2.z, B2.w, B3.x, B3.y, B3.z, B3.w};
      float p[NST];
      pow16(__builtin_amdgcn_exp2f(dt * Aa2[0]), p);
#pragma unroll
      for (int n = 0; n < NST; ++n) h[n] = fmaf(p[n], h[n], dtu * Bv[n]);
    }
  } else {
#pragma unroll 4
    for (int l = 0; l < LC; ++l) {
      float dt = h2f(*(const ushort*)(smem + 32768 + l * 512 +
                                      ((tid * 2) ^ (((l >> 2) & 3) << 5))));
      float u = bf2f(*(const ushort*)(smem + l * 512 +
                                      ((uchunk ^ (l & 7)) * 16) + uoff0));
      sdt += dt;
      float dtu = dt * u;
      const float* Bp = (const float*)(smem + 65536) + l * 32;
      f32x4 B0 = *(const f32x4*)(Bp);
      f32x4 B1 = *(const f32x4*)(Bp + 4);
      f32x4 B2 = *(const f32x4*)(Bp + 8);
      f32x4 B3 = *(const f32x4*)(Bp + 12);
      float Bv[NST] = {B0.x, B0.y, B0.z, B0.w, B1.x, B1.y, B1.z, B1.w,
                       B2.x, B2.y, B2.z, B2.w, B3.x, B3.y, B3.z, B3.w};
#pragma unroll
      for (int n = 0; n < NST; ++n) {
        float ab = __builtin_amdgcn_exp2f(dt * Aa2[n]);
        h[n] = fmaf(ab, h[n], dtu * Bv[n]);
      }
    }
  }
  float cum[NST];
  if (pm) {
    pow16(__builtin_amdgcn_exp2f(sdt * Aa2[0]), cum);
  } else {
#pragma unroll
    for (int n = 0; n < NST; ++n)
      cum[n] = __builtin_amdgcn_exp2f(sdt * Aa2[n]);
  }
  const size_t ob = (((size_t)(b * NCHUNK + c)) * DMODEL + tid) * NST;
#pragma unroll
  for (int q = 0; q < 4; ++q) {
    float4 hv = {h[q * 4 + 0], h[q * 4 + 1], h[q * 4 + 2], h[q * 4 + 3]};
    *(float4*)(hout + ob + q * 4) = hv;
    float4 cvv = {cum[q * 4 + 0], cum[q * 4 + 1], cum[q * 4 + 2],
                  cum[q * 4 + 3]};
    *(float4*)(cumA + ob + q * 4) = cvv;
  }
}

// ---------------------------------------------------------------------------
// Scan combine: sequential over chunks; in-place h_out -> h_in (fp32).
// ---------------------------------------------------------------------------
__global__ __launch_bounds__(256) void scan_combine(
    float* __restrict__ hstate, const float* __restrict__ cumA) {
  const int t = blockIdx.x * 256 + threadIdx.x;
  const int n = t & (NST - 1);
  const int dd = (t / NST) & (DMODEL - 1);
  const int b = t / (NST * DMODEL);
  float h = 0.f;
  for (int c = 0; c < NCHUNK; ++c) {
    size_t idx = (((size_t)(b * NCHUNK + c)) * DMODEL + dd) * NST + n;
    float ho = hstate[idx];
    float ca = cumA[idx];
    hstate[idx] = h;
    h = fmaf(ca, h, ho);
  }
}

// ---------------------------------------------------------------------------
// K3 fused_out: scan pass3 -> y_pre LDS tile -> GEMM with W_out -> d_out.
// LDS: @0 ypre bf16 [64][32c] swz c^(r&7) (32 KB); @32768 B dbuf 16KBx2;
//      @65536 BC f32 [64][32] (8 KB).
// ---------------------------------------------------------------------------
__global__ __launch_bounds__(256, 2) void fused_out(
    const ushort* __restrict__ dl, const ushort* __restrict__ xcb,
    const ushort* __restrict__ szy, const ushort* __restrict__ bcb,
    const float* __restrict__ A_log, const float* __restrict__ hin,
    const float* __restrict__ Dskip, const ushort* __restrict__ wout,
    const float* __restrict__ b_out, float* __restrict__ out) {
  __shared__ char smem[73728];
  const int tid = threadIdx.x, lane = tid & 63, wid = tid >> 6;
  const int b = blockIdx.x / NCHUNK, c = blockIdx.x % NCHUNK;
  const int l0 = c * LC;
  const size_t row0 = (size_t)b * LSEQ + l0;

  // stage BC f32 tile
#pragma unroll
  for (int i = 0; i < 2; ++i) {
    int t = tid + i * 256;
    int r = t >> 3, q = t & 7;
    uint2 v = *(const uint2*)(bcb + (row0 + r) * 32 + q * 4);
    float* dp = (float*)(smem + 65536) + r * 32 + q * 4;
    dp[0] = bf2f((ushort)(v.x & 0xffff));
    dp[1] = bf2f((ushort)(v.x >> 16));
    dp[2] = bf2f((ushort)(v.y & 0xffff));
    dp[3] = bf2f((ushort)(v.y >> 16));
  }
  // issue W_out k-step 0
  const int rB4 = tid >> 2, cB4 = tid & 3;
  const int sB4 = (rB4 + (rB4 >> 2)) & 3;
  const ushort* gB = wout + (size_t)rB4 * 256 + ((cB4 ^ sB4) * 8);
#pragma unroll
  for (int i = 0; i < 4; ++i)
    glds16(gB + (size_t)i * 64 * 256, smem + 32768 + i * 4096 + wid * 1024);

  float Aa2[NST];
#pragma unroll
  for (int q = 0; q < 4; ++q) {
    float4 v = *(const float4*)(A_log + tid * NST + q * 4);
    Aa2[q * 4 + 0] = -LOG2E * __expf(v.x);
    Aa2[q * 4 + 1] = -LOG2E * __expf(v.y);
    Aa2[q * 4 + 2] = -LOG2E * __expf(v.z);
    Aa2[q * 4 + 3] = -LOG2E * __expf(v.w);
  }
  bool pm = true;
#pragma unroll
  for (int n = 1; n < NST; ++n)
    pm = pm && (fabsf(Aa2[n] - (float)(n + 1) * Aa2[0]) <=
                1e-3f * fabsf(Aa2[n]));
  float h[NST];
  const size_t hb = (((size_t)(b * NCHUNK + c)) * DMODEL + tid) * NST;
#pragma unroll
  for (int q = 0; q < 4; ++q) {
    float4 v = *(const float4*)(hin + hb + q * 4);
    h[q * 4 + 0] = v.x;
    h[q * 4 + 1] = v.y;
    h[q * 4 + 2] = v.z;
    h[q * 4 + 3] = v.w;
  }
  const float dsk = Dskip[tid];
  __syncthreads();  // BC tile ready

  // ---- scan (global scalar reads w/ rolling prefetch), y_pre -> LDS
  const size_t base = row0 * DMODEL + tid;
  const int ywoff = (tid & 7) * 2;
  const int ywchunk = tid >> 3;
  ushort dtr[4], ur[4], zr[4];
#pragma unroll
  for (int j = 0; j < 4; ++j) {
    dtr[j] = dl[base + (size_t)j * DMODEL];
    ur[j] = xcb[base + (size_t)j * DMODEL];
    zr[j] = szy[base + (size_t)j * DMODEL];
  }
  for (int lb = 0; lb < LC / 4; ++lb) {
    ushort dtn[4], un[4], zn[4];
    if (lb < LC / 4 - 1) {
      size_t nb = base + (size_t)(lb * 4 + 4) * DMODEL;
#pragma unroll
      for (int j = 0; j < 4; ++j) {
        dtn[j] = dl[nb + (size_t)j * DMODEL];
        un[j] = xcb[nb + (size_t)j * DMODEL];
        zn[j] = szy[nb + (size_t)j * DMODEL];
      }
    }
#pragma unroll
    for (int j = 0; j < 4; ++j) {
      int l = lb * 4 + j;
      float dt = h2f(dtr[j]);
      float u = bf2f(ur[j]);
      float dtu = dt * u;
      const float* Bp = (const float*)(smem + 65536) + l * 32;
      f32x4 B0 = *(const f32x4*)(Bp);
      f32x4 B1 = *(const f32x4*)(Bp + 4);
      f32x4 B2 = *(const f32x4*)(Bp + 8);
      f32x4 B3 = *(const f32x4*)(Bp + 12);
      f32x4 C0 = *(const f32x4*)(Bp + 16);
      f32x4 C1 = *(const f32x4*)(Bp + 20);
      f32x4 C2 = *(const f32x4*)(Bp + 24);
      f32x4 C3 = *(const f32x4*)(Bp + 28);
      float Bv[NST] = {B0.x, B0.y, B0.z, B0.w, B1.x, B1.y, B1.z, B1.w,
                       B2.x, B2.y, B2.z, B2.w, B3.x, B3.y, B3.z, B3.w};
      float Cv[NST] = {C0.x, C0.y, C0.z, C0.w, C1.x, C1.y, C1.z, C1.w,
                       C2.x, C2.y, C2.z, C2.w, C3.x, C3.y, C3.z, C3.w};
      float y = 0.f;
      if (pm) {
        float p[NST];
        pow16(__builtin_amdgcn_exp2f(dt * Aa2[0]), p);
#pragma unroll
        for (int n = 0; n < NST; ++n) {
          h[n] = fmaf(p[n], h[n], dtu * Bv[n]);
          y = fmaf(h[n], Cv[n], y);
        }
      } else {
#pragma unroll
        for (int n = 0; n < NST; ++n) {
          float ab = __builtin_amdgcn_exp2f(dt * Aa2[n]);
          h[n] = fmaf(ab, h[n], dtu * Bv[n]);
          y = fmaf(h[n], Cv[n], y);
        }
      }
      float yp = (y + u * dsk) * bf2f(zr[j]);
      *(ushort*)(smem + l * 512 + ((ywchunk ^ (l & 7)) * 16) + ywoff) =
          (ushort)bf16rne(yp);
    }
#pragma unroll
    for (int j = 0; j < 4; ++j) {
      dtr[j] = dtn[j];
      ur[j] = un[j];
      zr[j] = zn[j];
    }
  }
  __syncthreads();  // ypre tile complete

  // ---- output GEMM: A = ypre tile, B = W_out streamed
  f32x4 acc[4][4];
#pragma unroll
  for (int i = 0; i < 4; ++i)
#pragma unroll
    for (int j = 0; j < 4; ++j) acc[i][j] = {0.f, 0.f, 0.f, 0.f};

  for (int step = 0; step < 8; ++step) {
    char* bufc = smem + 32768 + (step & 1) * 16384;
    if (step < 7) {
      char* bufn = smem + 32768 + ((step + 1) & 1) * 16384;
      const int k0 = (step + 1) * 32;
#pragma unroll
      for (int i = 0; i < 4; ++i)
        glds16(gB + (size_t)i * 64 * 256 + k0, bufn + i * 4096 + wid * 1024);
    }
    bf16x8 af[4], bfr[4];
#pragma unroll
    for (int i = 0; i < 4; ++i) {
      int r = i * 16 + (lane & 15);
      int sc = step * 4 + (lane >> 4);
      af[i] = *(const bf16x8*)(smem + r * 512 + ((sc ^ (r & 7)) * 16));
    }
#pragma unroll
    for (int j = 0; j < 4; ++j) {
      int r = wid * 64 + j * 16 + (lane & 15);
      int slot = (lane >> 4) ^ ((r + (r >> 2)) & 3);
      bfr[j] = *(const bf16x8*)(bufc + r * 64 + slot * 16);
    }
#pragma unroll
    for (int i = 0; i < 4; ++i)
#pragma unroll
      for (int j = 0; j < 4; ++j)
        acc[i][j] = __builtin_amdgcn_mfma_f32_16x16x32_bf16(af[i], bfr[j],
                                                            acc[i][j], 0, 0, 0);
    __syncthreads();
  }

  const int rbase = (lane >> 4) * 4;
  const int cn = lane & 15;
#pragma unroll
  for (int i = 0; i < 4; ++i)
#pragma unroll
    for (int j = 0; j < 4; ++j) {
      int col = wid * 64 + j * 16 + cn;
      float bs = b_out[col];
#pragma unroll
      for (int r = 0; r < 4; ++r) {
        int row = i * 16 + rbase + r;
        out[(row0 + row) * DMODEL + col] = acc[i][j][r] + bs;
      }
    }
}

// ---------------------------------------------------------------------------
extern "C" void kernel_launch(void* const* d_in, const int* in_sizes, int n_in,
                              void* d_out, int out_size, void* d_ws,
                              size_t ws_size, hipStream_t stream) {
  const float* x       = (const float*)d_in[0];
  const float* A_log   = (const float*)d_in[1];
  const float* D_skip  = (const float*)d_in[2];
  const float* W_B     = (const float*)d_in[3];
  const float* W_C     = (const float*)d_in[4];
  const float* W_delta = (const float*)d_in[5];
  const float* b_delta = (const float*)d_in[6];
  const float* W_in    = (const float*)d_in[7];
  const float* b_in    = (const float*)d_in[8];
  const float* W_out   = (const float*)d_in[9];
  const float* b_out   = (const float*)d_in[10];
  const float* conv_w  = (const float*)d_in[11];
  const float* conv_b  = (const float*)d_in[12];

  const size_t MD = (size_t)MROWS * DMODEL;                 // 16.78M
  const size_t HP = (size_t)BATCH * NCHUNK * DMODEL * NST;  // 4.19M
  float* xin   = (float*)d_ws;              // x_in fp32 [MD]
  ushort* dl   = (ushort*)(xin + MD);       // delta fp16 [MD]
  ushort* szy  = dl + MD;                   // silu(z) bf16 [MD]
  ushort* xcb  = szy + MD;                  // xc bf16 [MD]
  ushort* bcb  = xcb + MD;                  // bc bf16 [MROWS*32]
  float* hst   = (float*)(bcb + (size_t)MROWS * 32);  // h_out -> h_in [HP]
  float* cumA  = hst + HP;                  // [HP]
  ushort* wbf  = (ushort*)(cumA + HP);      // bf16 weights, 270336

  cvt_weights<<<dim3(132), 256, 0, stream>>>(W_in, W_delta, W_out, W_B, W_C, wbf);
  gemm_in<<<dim3(2, MROWS / 64), 256, 0, stream>>>(x, wbf, b_in, xin, szy);
  fused_mid<<<dim3(BATCH * NCHUNK), 256, 0, stream>>>(
      xin, wbf + 131072, wbf + 262144, b_delta, A_log, conv_w, conv_b,
      xcb, dl, bcb, hst, cumA);
  scan_combine<<<dim3(BATCH * DMODEL * NST / 256), 256, 0, stream>>>(hst, cumA);
  fused_out<<<dim3(BATCH * NCHUNK), 256, 0, stream>>>(
      dl, xcb, szy, bcb, A_log, hst, D_skip, wbf + 196608, b_out,
      (float*)d_out);
}